// Round 1
// baseline (18179.640 us; speedup 1.0000x reference)
//
#include <hip/hip_runtime.h>
#include <math.h>

#define B_ 4
#define N_ 4096
#define D_ 1024
#define H_ 16
#define DH_ 64
#define M_ 266

#define DN_ 0.35355339059327373f      // 64^-0.25
#define RATIO_ 0.06131393394849658f   // 266^-0.5
#define EPS_ 1e-4f

// ---------- utility: ordered-uint encoding for float atomicMax ----------
__device__ __forceinline__ unsigned f2ord(float f) {
    unsigned u = __float_as_uint(f);
    return (u & 0x80000000u) ? ~u : (u | 0x80000000u);
}
__device__ __forceinline__ float ord2f(unsigned u) {
    unsigned b = (u & 0x80000000u) ? (u & 0x7fffffffu) : ~u;
    return __uint_as_float(b);
}

__global__ void zero_kernel(float* __restrict__ p, int n) {
    int i = blockIdx.x * 256 + threadIdx.x;
    if (i < n) p[i] = 0.f;
}

// ---------------- fp32 GEMM: C[M,N] = A[M,K] @ B[N,K]^T + bias, opt relu ----------------
#define BM 128
#define BN 64
#define BK 16

__global__ __launch_bounds__(256) void gemm_nt(const float* __restrict__ A,
        const float* __restrict__ Bw, const float* __restrict__ bias,
        float* __restrict__ C, int Kdim, int Ncols, int relu)
{
    __shared__ float As[BK][BM + 4];
    __shared__ float Bs[BK][BN + 4];
    int tid = threadIdx.x;
    int bm = blockIdx.y * BM;
    int bn = blockIdx.x * BN;
    int tx = tid & 15;   // n micro: 4 cols
    int ty = tid >> 4;   // m micro: 8 rows

    float acc[8][4];
    #pragma unroll
    for (int i = 0; i < 8; ++i)
        #pragma unroll
        for (int j = 0; j < 4; ++j) acc[i][j] = 0.f;

    const float* Aptr = A + (size_t)bm * Kdim;
    const float* Bptr = Bw + (size_t)bn * Kdim;

    for (int kt = 0; kt < Kdim; kt += BK) {
        #pragma unroll
        for (int l = 0; l < 2; ++l) {
            int idx = tid + 256 * l;          // 512 float4 = 128 rows x 16k
            int row = idx >> 2;
            int k4 = (idx & 3) * 4;
            const float4 a = *(const float4*)(Aptr + (size_t)row * Kdim + kt + k4);
            As[k4 + 0][row] = a.x; As[k4 + 1][row] = a.y;
            As[k4 + 2][row] = a.z; As[k4 + 3][row] = a.w;
        }
        {
            int row = tid >> 2;               // 256 float4 = 64 rows x 16k
            int k4 = (tid & 3) * 4;
            const float4 b = *(const float4*)(Bptr + (size_t)row * Kdim + kt + k4);
            Bs[k4 + 0][row] = b.x; Bs[k4 + 1][row] = b.y;
            Bs[k4 + 2][row] = b.z; Bs[k4 + 3][row] = b.w;
        }
        __syncthreads();
        #pragma unroll
        for (int kk = 0; kk < BK; ++kk) {
            const float4 a0 = *(const float4*)&As[kk][ty * 8];
            const float4 a1 = *(const float4*)&As[kk][ty * 8 + 4];
            const float4 b0 = *(const float4*)&Bs[kk][tx * 4];
            float av[8] = {a0.x, a0.y, a0.z, a0.w, a1.x, a1.y, a1.z, a1.w};
            float bv[4] = {b0.x, b0.y, b0.z, b0.w};
            #pragma unroll
            for (int i = 0; i < 8; ++i)
                #pragma unroll
                for (int j = 0; j < 4; ++j)
                    acc[i][j] = fmaf(av[i], bv[j], acc[i][j]);
        }
        __syncthreads();
    }
    const float4 bb = *(const float4*)(bias + bn + tx * 4);
    #pragma unroll
    for (int i = 0; i < 8; ++i) {
        int row = bm + ty * 8 + i;
        float4 o;
        o.x = acc[i][0] + bb.x; o.y = acc[i][1] + bb.y;
        o.z = acc[i][2] + bb.z; o.w = acc[i][3] + bb.w;
        if (relu) {
            o.x = fmaxf(o.x, 0.f); o.y = fmaxf(o.y, 0.f);
            o.z = fmaxf(o.z, 0.f); o.w = fmaxf(o.w, 0.f);
        }
        *(float4*)(C + (size_t)row * Ncols + bn + tx * 4) = o;
    }
}

// ---------------- key side: accumulate S_u[m]=SUM exp(td-diag), C_u[m,dh]=SUM exp()*v, Vsum[dh], max(td) ----------------
// grid: x = nsplit(8, 512 rows each), y = mtile(5, 64 wide), z = bh(64)
__global__ __launch_bounds__(256) void kside(
    const float* __restrict__ Kin, const float* __restrict__ Vin,
    const float* __restrict__ proj,
    float* __restrict__ S_u, float* __restrict__ C_u,
    float* __restrict__ Vsum, unsigned int* __restrict__ mxp)
{
    int bh = blockIdx.z;
    int b = bh >> 4, h = bh & 15;
    int m0 = blockIdx.y * 64;
    int mwidth = min(64, M_ - m0);
    int n0 = blockIdx.x * 512;
    int tid = threadIdx.x;

    __shared__ float projT[64][68];   // [d][mm]
    __shared__ float KsT[64][34];     // [d][r]
    __shared__ float Vs[32][68];      // [r][dh]
    __shared__ float Ss[32][68];      // [r][mm]
    __shared__ float diag[32];
    __shared__ float red[256];

    for (int i = tid; i < 64 * 64; i += 256) {
        int mm = i >> 6, d = i & 63;
        projT[d][mm] = (mm < mwidth) ? proj[(m0 + mm) * 64 + d] : 0.f;
    }

    int rq = tid >> 4;   // 0..15 -> rows rq*2 .. +1
    int mq = tid & 15;   // -> m = mq*4 .. +3  (same grouping reused as tm/tdh)
    int tm = tid & 15;
    int tdh = tid >> 4;
    bool isMT0 = (blockIdx.y == 0);

    float cacc[4][4];
    #pragma unroll
    for (int i = 0; i < 4; ++i)
        #pragma unroll
        for (int j = 0; j < 4; ++j) cacc[i][j] = 0.f;
    float vsum[4] = {0.f, 0.f, 0.f, 0.f};
    float ksum[4] = {0.f, 0.f, 0.f, 0.f};
    float lmax = -1e30f;
    bool mvalid[4];
    #pragma unroll
    for (int j = 0; j < 4; ++j) mvalid[j] = (mq * 4 + j) < mwidth;

    for (int nc = 0; nc < 512; nc += 32) {
        __syncthreads();   // protect tiles from previous iteration (also orders projT load)
        #pragma unroll
        for (int l = 0; l < 2; ++l) {
            int idx = tid + 256 * l;   // 512 float4 = 32 rows x 64 d
            int r = idx >> 4;
            int d4 = (idx & 15) * 4;
            size_t gro = ((size_t)(b * N_ + n0 + nc + r)) * D_ + h * DH_ + d4;
            const float4 kv = *(const float4*)(Kin + gro);
            KsT[d4 + 0][r] = kv.x; KsT[d4 + 1][r] = kv.y;
            KsT[d4 + 2][r] = kv.z; KsT[d4 + 3][r] = kv.w;
            const float4 vv = *(const float4*)(Vin + gro);
            *(float4*)&Vs[r][d4] = vv;
        }
        __syncthreads();
        {
            int r = tid & 31, part = tid >> 5;
            float s = 0.f;
            #pragma unroll
            for (int dd = 0; dd < 8; ++dd) {
                float kv = KsT[part * 8 + dd][r];
                s = fmaf(kv, kv, s);
            }
            red[tid] = s;
        }
        __syncthreads();
        if (tid < 32) {
            float s = 0.f;
            #pragma unroll
            for (int p = 0; p < 8; ++p) s += red[tid + 32 * p];
            diag[tid] = s * 0.0625f;   // 0.5*dn^2 = 1/16
        }
        __syncthreads();
        float td[2][4];
        #pragma unroll
        for (int i = 0; i < 2; ++i)
            #pragma unroll
            for (int j = 0; j < 4; ++j) td[i][j] = 0.f;
        #pragma unroll 8
        for (int d = 0; d < 64; ++d) {
            const float2 kk = *(const float2*)&KsT[d][rq * 2];
            const float4 p4 = *(const float4*)&projT[d][mq * 4];
            float pv[4] = {p4.x, p4.y, p4.z, p4.w};
            #pragma unroll
            for (int j = 0; j < 4; ++j) {
                td[0][j] = fmaf(kk.x, pv[j], td[0][j]);
                td[1][j] = fmaf(kk.y, pv[j], td[1][j]);
            }
        }
        #pragma unroll
        for (int i = 0; i < 2; ++i) {
            int r = rq * 2 + i;
            float dg = diag[r];
            #pragma unroll
            for (int j = 0; j < 4; ++j) {
                float t = td[i][j] * DN_;
                float s = 0.f;
                if (mvalid[j]) {
                    lmax = fmaxf(lmax, t);
                    s = expf(t - dg);
                }
                Ss[r][mq * 4 + j] = s;
                ksum[j] += s;
            }
        }
        __syncthreads();
        for (int r = 0; r < 32; ++r) {
            const float4 s4 = *(const float4*)&Ss[r][tm * 4];
            const float4 v4 = *(const float4*)&Vs[r][tdh * 4];
            float sv[4] = {s4.x, s4.y, s4.z, s4.w};
            float vv[4] = {v4.x, v4.y, v4.z, v4.w};
            #pragma unroll
            for (int i = 0; i < 4; ++i)
                #pragma unroll
                for (int j = 0; j < 4; ++j)
                    cacc[i][j] = fmaf(sv[i], vv[j], cacc[i][j]);
            if (isMT0 && tm == 0) {
                #pragma unroll
                for (int j = 0; j < 4; ++j) vsum[j] += vv[j];
            }
        }
    }
    // reduce ksum over rq groups -> S_u
    for (int j = 0; j < 4; ++j) {
        __syncthreads();
        red[tid] = ksum[j];
        __syncthreads();
        if (tid < 16) {
            float s = 0.f;
            #pragma unroll
            for (int q = 0; q < 16; ++q) s += red[q * 16 + tid];
            if (tid * 4 + j < mwidth)
                atomicAdd(S_u + bh * M_ + m0 + tid * 4 + j, s);
        }
    }
    // block max -> mx
    __syncthreads();
    red[tid] = lmax;
    __syncthreads();
    for (int s = 128; s > 0; s >>= 1) {
        if (tid < s) red[tid] = fmaxf(red[tid], red[tid + s]);
        __syncthreads();
    }
    if (tid == 0) atomicMax(mxp + bh, f2ord(red[0]));
    // cacc -> C_u
    #pragma unroll
    for (int i = 0; i < 4; ++i) {
        int m = tm * 4 + i;
        if (m < mwidth) {
            #pragma unroll
            for (int j = 0; j < 4; ++j)
                atomicAdd(C_u + ((size_t)bh * M_ + m0 + m) * 64 + tdh * 4 + j, cacc[i][j]);
        }
    }
    if (isMT0 && tm == 0) {
        #pragma unroll
        for (int j = 0; j < 4; ++j)
            atomicAdd(Vsum + bh * 64 + tdh * 4 + j, vsum[j]);
    }
}

// ---------------- finalize: apply e^{-mx}, EPS, ratio ----------------
__global__ __launch_bounds__(256) void finalize_kernel(
    const float* __restrict__ S_u, const float* __restrict__ C_u,
    const float* __restrict__ Vsum, const unsigned* __restrict__ mxp,
    float* __restrict__ ksum_f, float* __restrict__ ctx_f)
{
    int bh = blockIdx.x;
    int tid = threadIdx.x;
    float emx = expf(-ord2f(mxp[bh]));
    for (int i = tid; i < M_ * 64; i += 256) {
        int dh = i & 63;
        ctx_f[(size_t)bh * M_ * 64 + i] =
            RATIO_ * (emx * C_u[(size_t)bh * M_ * 64 + i] + EPS_ * Vsum[bh * 64 + dh]);
    }
    for (int m = tid; m < M_; m += 256)
        ksum_f[bh * M_ + m] = RATIO_ * (emx * S_u[bh * M_ + m] + EPS_ * (float)N_);
}

// ---------------- query side: qp, d_inv, out = (qp @ ctx) * d_inv ----------------
// grid: x = ntile (128, 32 rows), y = bh (64)
__global__ __launch_bounds__(256) void qside(
    const float* __restrict__ Q, const float* __restrict__ proj,
    const float* __restrict__ ksum_f, const float* __restrict__ ctx_f,
    float* __restrict__ attn)
{
    int bh = blockIdx.y;
    int b = bh >> 4, h = bh & 15;
    int n0 = blockIdx.x * 32;
    int tid = threadIdx.x;

    __shared__ float QsT[64][34];    // [d][r]
    __shared__ float buf[64][68];    // projT chunk, then ctx chunk
    __shared__ float qp[32][268];    // td then qp
    __shared__ float ks[268];
    __shared__ float diag[32], rmax[32], dinv[32];
    __shared__ float red[256];

    #pragma unroll
    for (int l = 0; l < 2; ++l) {
        int idx = tid + 256 * l;
        int r = idx >> 4;
        int d4 = (idx & 15) * 4;
        const float4 qv = *(const float4*)(Q + ((size_t)(b * N_ + n0 + r)) * D_ + h * DH_ + d4);
        QsT[d4 + 0][r] = qv.x; QsT[d4 + 1][r] = qv.y;
        QsT[d4 + 2][r] = qv.z; QsT[d4 + 3][r] = qv.w;
    }
    for (int m = tid; m < 268; m += 256) ks[m] = (m < M_) ? ksum_f[bh * M_ + m] : 0.f;
    __syncthreads();
    {
        int r = tid & 31, part = tid >> 5;
        float s = 0.f;
        #pragma unroll
        for (int dd = 0; dd < 8; ++dd) { float qv = QsT[part * 8 + dd][r]; s = fmaf(qv, qv, s); }
        red[tid] = s;
    }
    __syncthreads();
    if (tid < 32) {
        float s = 0.f;
        #pragma unroll
        for (int p = 0; p < 8; ++p) s += red[tid + 32 * p];
        diag[tid] = s * 0.0625f;
    }
    int rq = tid >> 4, mq = tid & 15;
    for (int mc = 0; mc < 5; ++mc) {
        int mbase = mc * 64;
        int mw = min(64, M_ - mbase);
        __syncthreads();
        for (int i = tid; i < 64 * 64; i += 256) {
            int mm = i >> 6, d = i & 63;
            buf[d][mm] = (mm < mw) ? proj[(mbase + mm) * 64 + d] : 0.f;
        }
        __syncthreads();
        float td[2][4];
        #pragma unroll
        for (int i = 0; i < 2; ++i)
            #pragma unroll
            for (int j = 0; j < 4; ++j) td[i][j] = 0.f;
        #pragma unroll 8
        for (int d = 0; d < 64; ++d) {
            const float2 qq = *(const float2*)&QsT[d][rq * 2];
            const float4 p4 = *(const float4*)&buf[d][mq * 4];
            float pv[4] = {p4.x, p4.y, p4.z, p4.w};
            #pragma unroll
            for (int j = 0; j < 4; ++j) {
                td[0][j] = fmaf(qq.x, pv[j], td[0][j]);
                td[1][j] = fmaf(qq.y, pv[j], td[1][j]);
            }
        }
        #pragma unroll
        for (int i = 0; i < 2; ++i)
            #pragma unroll
            for (int j = 0; j < 4; ++j)
                if (mq * 4 + j < mw)
                    qp[rq * 2 + i][mbase + mq * 4 + j] = td[i][j] * DN_;
    }
    __syncthreads();
    {
        int r = tid >> 3, part = tid & 7;
        float mxv = -1e30f;
        for (int m = part; m < M_; m += 8) mxv = fmaxf(mxv, qp[r][m]);
        red[tid] = mxv;
    }
    __syncthreads();
    if (tid < 32) {
        float mxv = red[tid * 8];
        #pragma unroll
        for (int p = 1; p < 8; ++p) mxv = fmaxf(mxv, red[tid * 8 + p]);
        rmax[tid] = mxv;
    }
    __syncthreads();
    {
        int r = tid >> 3, part = tid & 7;
        float dg = diag[r], mxv = rmax[r];
        float dacc = 0.f;
        for (int m = part; m < M_; m += 8) {
            float val = RATIO_ * (expf(qp[r][m] - dg - mxv) + EPS_);
            qp[r][m] = val;
            dacc = fmaf(val, ks[m], dacc);
        }
        red[tid] = dacc;
    }
    __syncthreads();
    if (tid < 32) {
        float s = red[tid * 8];
        #pragma unroll
        for (int p = 1; p < 8; ++p) s += red[tid * 8 + p];
        dinv[tid] = 1.f / s;
    }
    // out = qp @ ctx
    int dq = tid & 15;    // dh = dq*4
    int rq2 = tid >> 4;   // r = rq2*2 .. +1
    float oacc[2][4];
    #pragma unroll
    for (int i = 0; i < 2; ++i)
        #pragma unroll
        for (int j = 0; j < 4; ++j) oacc[i][j] = 0.f;
    for (int mc = 0; mc < 5; ++mc) {
        int mbase = mc * 64;
        int mw = min(64, M_ - mbase);
        __syncthreads();
        for (int i = tid; i < 64 * 64; i += 256) {
            int mm = i >> 6, dh = i & 63;
            buf[mm][dh] = (mm < mw) ? ctx_f[((size_t)bh * M_ + mbase + mm) * 64 + dh] : 0.f;
        }
        __syncthreads();
        for (int mm = 0; mm < mw; ++mm) {
            float s0 = qp[rq2 * 2][mbase + mm];
            float s1 = qp[rq2 * 2 + 1][mbase + mm];
            const float4 c4 = *(const float4*)&buf[mm][dq * 4];
            float cv[4] = {c4.x, c4.y, c4.z, c4.w};
            #pragma unroll
            for (int j = 0; j < 4; ++j) {
                oacc[0][j] = fmaf(s0, cv[j], oacc[0][j]);
                oacc[1][j] = fmaf(s1, cv[j], oacc[1][j]);
            }
        }
    }
    #pragma unroll
    for (int i = 0; i < 2; ++i) {
        int r = rq2 * 2 + i;
        float di = dinv[r];
        float4 o;
        o.x = oacc[i][0] * di; o.y = oacc[i][1] * di;
        o.z = oacc[i][2] * di; o.w = oacc[i][3] * di;
        *(float4*)(attn + ((size_t)(b * N_ + n0 + r)) * D_ + h * DH_ + dq * 4) = o;
    }
}

// ---------------- launch ----------------
extern "C" void kernel_launch(void* const* d_in, const int* in_sizes, int n_in,
                              void* d_out, int out_size, void* d_ws, size_t ws_size,
                              hipStream_t stream)
{
    const float* x    = (const float*)d_in[0];
    const float* Wq   = (const float*)d_in[1];
    const float* bq   = (const float*)d_in[2];
    const float* Wk   = (const float*)d_in[3];
    const float* bk   = (const float*)d_in[4];
    const float* Wv   = (const float*)d_in[5];
    const float* bv   = (const float*)d_in[6];
    const float* Wo   = (const float*)d_in[7];
    const float* bo   = (const float*)d_in[8];
    const float* Wfc  = (const float*)d_in[9];
    const float* bfc  = (const float*)d_in[10];
    const float* proj = (const float*)d_in[11];
    float* out = (float*)d_out;

    float* ws = (float*)d_ws;
    const size_t nTok = (size_t)B_ * N_ * D_;       // 16,777,216
    const size_t offQ = 0;
    const size_t offK = nTok;
    const size_t offV = nTok * 2;
    const size_t nSu = 64 * M_;                     // 17,024
    const size_t nCu = (size_t)64 * M_ * 64;        // 1,089,536
    const size_t nVs = 64 * 64;
    const size_t nMx = 64;
    const size_t offSu = nTok * 3;
    const size_t offCu = offSu + nSu;
    const size_t offVs = offCu + nCu;
    const size_t offMx = offVs + nVs;
    const size_t offKsf = offMx + nMx;
    const size_t offCtxf = offKsf + nSu;

    float* Q    = ws + offQ;
    float* Kb   = ws + offK;
    float* Vb   = ws + offV;
    float* S_u  = ws + offSu;
    float* C_u  = ws + offCu;
    float* Vsum = ws + offVs;
    unsigned* mx = (unsigned*)(ws + offMx);
    float* ksf  = ws + offKsf;
    float* ctxf = ws + offCtxf;
    float* attn = Kb;   // K no longer needed after kside
    float* hbuf = Vb;   // V no longer needed after kside

    int nzero = (int)(nSu + nCu + nVs + nMx);
    zero_kernel<<<dim3((nzero + 255) / 256), dim3(256), 0, stream>>>(S_u, nzero);

    dim3 gg(D_ / BN, (B_ * N_) / BM);   // 16 x 128
    gemm_nt<<<gg, dim3(256), 0, stream>>>(x, Wq, bq, Q, D_, D_, 0);
    gemm_nt<<<gg, dim3(256), 0, stream>>>(x, Wk, bk, Kb, D_, D_, 0);
    gemm_nt<<<gg, dim3(256), 0, stream>>>(x, Wv, bv, Vb, D_, D_, 0);

    kside<<<dim3(8, 5, 64), dim3(256), 0, stream>>>(Kb, Vb, proj, S_u, C_u, Vsum, mx);
    finalize_kernel<<<dim3(64), dim3(256), 0, stream>>>(S_u, C_u, Vsum, mx, ksf, ctxf);
    qside<<<dim3(128, 64), dim3(256), 0, stream>>>(Q, proj, ksf, ctxf, attn);

    gemm_nt<<<gg, dim3(256), 0, stream>>>(attn, Wo, bo, hbuf, D_, D_, 0);
    gemm_nt<<<gg, dim3(256), 0, stream>>>(hbuf, Wfc, bfc, out, D_, D_, 1);
}

// Round 3
// 3142.509 us; speedup vs baseline: 5.7851x; 5.7851x over previous
//
#include <hip/hip_runtime.h>
#include <math.h>

#define B_ 4
#define N_ 4096
#define D_ 1024
#define H_ 16
#define DH_ 64
#define M_ 266
#define MP_ 320   // M padded to 5 chunks of 64 (qattn iterates 5*64)

#define DN_ 0.35355339059327373f      // 64^-0.25
#define RATIO_ 0.06131393394849658f   // 266^-0.5
#define EPS_ 1e-4f

// ---------- ordered-uint encoding for float atomicMax ----------
__device__ __forceinline__ unsigned f2ord(float f) {
    unsigned u = __float_as_uint(f);
    return (u & 0x80000000u) ? ~u : (u | 0x80000000u);
}
__device__ __forceinline__ float ord2f(unsigned u) {
    unsigned b = (u & 0x80000000u) ? (u & 0x7fffffffu) : ~u;
    return __uint_as_float(b);
}

__global__ void zero_kernel(float* __restrict__ p, int n) {
    int i = blockIdx.x * 256 + threadIdx.x;
    if (i < n) p[i] = 0.f;
}

// ---------------- fp32 GEMM: C[M,N] = A[M,K] @ B[N,K]^T + bias, opt relu ----------------
#define BM 128
#define BN 64
#define BK 16

__global__ __launch_bounds__(256) void gemm_nt(const float* __restrict__ A,
        const float* __restrict__ Bw, const float* __restrict__ bias,
        float* __restrict__ C, int Kdim, int Ncols, int relu)
{
    __shared__ float As[BK][BM + 4];
    __shared__ float Bs[BK][BN + 4];
    int tid = threadIdx.x;
    int bm = blockIdx.y * BM;
    int bn = blockIdx.x * BN;
    int tx = tid & 15;   // n micro: 4 cols
    int ty = tid >> 4;   // m micro: 8 rows

    float acc[8][4];
    #pragma unroll
    for (int i = 0; i < 8; ++i)
        #pragma unroll
        for (int j = 0; j < 4; ++j) acc[i][j] = 0.f;

    const float* Aptr = A + (size_t)bm * Kdim;
    const float* Bptr = Bw + (size_t)bn * Kdim;

    for (int kt = 0; kt < Kdim; kt += BK) {
        #pragma unroll
        for (int l = 0; l < 2; ++l) {
            int idx = tid + 256 * l;          // 512 float4 = 128 rows x 16k
            int row = idx >> 2;
            int k4 = (idx & 3) * 4;
            const float4 a = *(const float4*)(Aptr + (size_t)row * Kdim + kt + k4);
            As[k4 + 0][row] = a.x; As[k4 + 1][row] = a.y;
            As[k4 + 2][row] = a.z; As[k4 + 3][row] = a.w;
        }
        {
            int row = tid >> 2;               // 256 float4 = 64 rows x 16k
            int k4 = (tid & 3) * 4;
            const float4 b = *(const float4*)(Bptr + (size_t)row * Kdim + kt + k4);
            Bs[k4 + 0][row] = b.x; Bs[k4 + 1][row] = b.y;
            Bs[k4 + 2][row] = b.z; Bs[k4 + 3][row] = b.w;
        }
        __syncthreads();
        #pragma unroll
        for (int kk = 0; kk < BK; ++kk) {
            const float4 a0 = *(const float4*)&As[kk][ty * 8];
            const float4 a1 = *(const float4*)&As[kk][ty * 8 + 4];
            const float4 b0 = *(const float4*)&Bs[kk][tx * 4];
            float av[8] = {a0.x, a0.y, a0.z, a0.w, a1.x, a1.y, a1.z, a1.w};
            float bv[4] = {b0.x, b0.y, b0.z, b0.w};
            #pragma unroll
            for (int i = 0; i < 8; ++i)
                #pragma unroll
                for (int j = 0; j < 4; ++j)
                    acc[i][j] = fmaf(av[i], bv[j], acc[i][j]);
        }
        __syncthreads();
    }
    const float4 bb = *(const float4*)(bias + bn + tx * 4);
    #pragma unroll
    for (int i = 0; i < 8; ++i) {
        int row = bm + ty * 8 + i;
        float4 o;
        o.x = acc[i][0] + bb.x; o.y = acc[i][1] + bb.y;
        o.z = acc[i][2] + bb.z; o.w = acc[i][3] + bb.w;
        if (relu) {
            o.x = fmaxf(o.x, 0.f); o.y = fmaxf(o.y, 0.f);
            o.z = fmaxf(o.z, 0.f); o.w = fmaxf(o.w, 0.f);
        }
        *(float4*)(C + (size_t)row * Ncols + bn + tx * 4) = o;
    }
}

// ---------------- key side: S_u[m]=SUM exp(td-diag), C_u[m,dh]=SUM exp()*v, Vsum[dh], max(td) ----------------
// grid: x = nsplit(8, 512 rows each), y = mtile(5, 64 wide), z = bh(64)
__global__ __launch_bounds__(256) void kside(
    const float* __restrict__ Kin, const float* __restrict__ Vin,
    const float* __restrict__ proj,
    float* __restrict__ S_u, float* __restrict__ C_u,
    float* __restrict__ Vsum, unsigned int* __restrict__ mxp)
{
    int bh = blockIdx.z;
    int b = bh >> 4, h = bh & 15;
    int m0 = blockIdx.y * 64;
    int mwidth = min(64, M_ - m0);
    int n0 = blockIdx.x * 512;
    int tid = threadIdx.x;

    __shared__ float projT[64][68];   // [d][mm]
    __shared__ float KsT[64][34];     // [d][r]
    __shared__ float Vs[32][68];      // [r][dh]
    __shared__ float Ss[32][68];      // [r][mm]
    __shared__ float diag[32];
    __shared__ float red[256];

    for (int i = tid; i < 64 * 64; i += 256) {
        int mm = i >> 6, d = i & 63;
        projT[d][mm] = (mm < mwidth) ? proj[(m0 + mm) * 64 + d] : 0.f;
    }

    int rq = tid >> 4;
    int mq = tid & 15;
    int tm = tid & 15;
    int tdh = tid >> 4;
    bool isMT0 = (blockIdx.y == 0);

    float cacc[4][4];
    #pragma unroll
    for (int i = 0; i < 4; ++i)
        #pragma unroll
        for (int j = 0; j < 4; ++j) cacc[i][j] = 0.f;
    float vsum[4] = {0.f, 0.f, 0.f, 0.f};
    float ksum[4] = {0.f, 0.f, 0.f, 0.f};
    float lmax = -1e30f;
    bool mvalid[4];
    #pragma unroll
    for (int j = 0; j < 4; ++j) mvalid[j] = (mq * 4 + j) < mwidth;

    for (int nc = 0; nc < 512; nc += 32) {
        __syncthreads();
        #pragma unroll
        for (int l = 0; l < 2; ++l) {
            int idx = tid + 256 * l;
            int r = idx >> 4;
            int d4 = (idx & 15) * 4;
            size_t gro = ((size_t)(b * N_ + n0 + nc + r)) * D_ + h * DH_ + d4;
            const float4 kv = *(const float4*)(Kin + gro);
            KsT[d4 + 0][r] = kv.x; KsT[d4 + 1][r] = kv.y;
            KsT[d4 + 2][r] = kv.z; KsT[d4 + 3][r] = kv.w;
            const float4 vv = *(const float4*)(Vin + gro);
            *(float4*)&Vs[r][d4] = vv;
        }
        __syncthreads();
        {
            int r = tid & 31, part = tid >> 5;
            float s = 0.f;
            #pragma unroll
            for (int dd = 0; dd < 8; ++dd) {
                float kv = KsT[part * 8 + dd][r];
                s = fmaf(kv, kv, s);
            }
            red[tid] = s;
        }
        __syncthreads();
        if (tid < 32) {
            float s = 0.f;
            #pragma unroll
            for (int p = 0; p < 8; ++p) s += red[tid + 32 * p];
            diag[tid] = s * 0.0625f;
        }
        __syncthreads();
        float td[2][4];
        #pragma unroll
        for (int i = 0; i < 2; ++i)
            #pragma unroll
            for (int j = 0; j < 4; ++j) td[i][j] = 0.f;
        #pragma unroll 8
        for (int d = 0; d < 64; ++d) {
            const float2 kk = *(const float2*)&KsT[d][rq * 2];
            const float4 p4 = *(const float4*)&projT[d][mq * 4];
            float pv[4] = {p4.x, p4.y, p4.z, p4.w};
            #pragma unroll
            for (int j = 0; j < 4; ++j) {
                td[0][j] = fmaf(kk.x, pv[j], td[0][j]);
                td[1][j] = fmaf(kk.y, pv[j], td[1][j]);
            }
        }
        #pragma unroll
        for (int i = 0; i < 2; ++i) {
            int r = rq * 2 + i;
            float dg = diag[r];
            #pragma unroll
            for (int j = 0; j < 4; ++j) {
                float t = td[i][j] * DN_;
                float s = 0.f;
                if (mvalid[j]) {
                    lmax = fmaxf(lmax, t);
                    s = expf(t - dg);
                }
                Ss[r][mq * 4 + j] = s;
                ksum[j] += s;
            }
        }
        __syncthreads();
        for (int r = 0; r < 32; ++r) {
            const float4 s4 = *(const float4*)&Ss[r][tm * 4];
            const float4 v4 = *(const float4*)&Vs[r][tdh * 4];
            float sv[4] = {s4.x, s4.y, s4.z, s4.w};
            float vv[4] = {v4.x, v4.y, v4.z, v4.w};
            #pragma unroll
            for (int i = 0; i < 4; ++i)
                #pragma unroll
                for (int j = 0; j < 4; ++j)
                    cacc[i][j] = fmaf(sv[i], vv[j], cacc[i][j]);
            if (isMT0 && tm == 0) {
                #pragma unroll
                for (int j = 0; j < 4; ++j) vsum[j] += vv[j];
            }
        }
    }
    for (int j = 0; j < 4; ++j) {
        __syncthreads();
        red[tid] = ksum[j];
        __syncthreads();
        if (tid < 16) {
            float s = 0.f;
            #pragma unroll
            for (int q = 0; q < 16; ++q) s += red[q * 16 + tid];
            if (tid * 4 + j < mwidth)
                atomicAdd(S_u + bh * M_ + m0 + tid * 4 + j, s);
        }
    }
    __syncthreads();
    red[tid] = lmax;
    __syncthreads();
    for (int s = 128; s > 0; s >>= 1) {
        if (tid < s) red[tid] = fmaxf(red[tid], red[tid + s]);
        __syncthreads();
    }
    if (tid == 0) atomicMax(mxp + bh, f2ord(red[0]));
    #pragma unroll
    for (int i = 0; i < 4; ++i) {
        int m = tm * 4 + i;
        if (m < mwidth) {
            #pragma unroll
            for (int j = 0; j < 4; ++j)
                atomicAdd(C_u + ((size_t)bh * M_ + m0 + m) * 64 + tdh * 4 + j, cacc[i][j]);
        }
    }
    if (isMT0 && tm == 0) {
        #pragma unroll
        for (int j = 0; j < 4; ++j)
            atomicAdd(Vsum + bh * 64 + tdh * 4 + j, vsum[j]);
    }
}

// ---------------- finalize: ctx (zero-padded to MP_ rows), ks (padded), Cs = sum_m ctx, kss = sum_m ks ----------------
__global__ __launch_bounds__(256) void finalize_kernel(
    const float* __restrict__ S_u, const float* __restrict__ C_u,
    const float* __restrict__ Vsum, const unsigned* __restrict__ mxp,
    float* __restrict__ ksum_f, float* __restrict__ ctx_f,
    float* __restrict__ Cs, float* __restrict__ kss)
{
    __shared__ float red[256];
    int bh = blockIdx.x;
    int tid = threadIdx.x;
    float emx = expf(-ord2f(mxp[bh]));
    for (int i = tid; i < MP_ * 64; i += 256) {
        int m = i >> 6, dh = i & 63;
        float v = 0.f;
        if (m < M_)
            v = RATIO_ * (emx * C_u[((size_t)bh * M_ + m) * 64 + dh] + EPS_ * Vsum[bh * 64 + dh]);
        ctx_f[(size_t)bh * MP_ * 64 + i] = v;
    }
    for (int m = tid; m < MP_; m += 256)
        ksum_f[bh * MP_ + m] = (m < M_) ? RATIO_ * (emx * S_u[bh * M_ + m] + EPS_ * (float)N_) : 0.f;

    // Cs[dh] = sum_m ctx
    {
        int dh = tid & 63, part = tid >> 6;
        float s = 0.f;
        for (int m = part; m < M_; m += 4)
            s += RATIO_ * (emx * C_u[((size_t)bh * M_ + m) * 64 + dh] + EPS_ * Vsum[bh * 64 + dh]);
        red[tid] = s;
    }
    __syncthreads();
    if (tid < 64) Cs[bh * 64 + tid] = red[tid] + red[tid + 64] + red[tid + 128] + red[tid + 192];
    __syncthreads();
    // kss = sum_m ks
    {
        float s = 0.f;
        for (int m = tid; m < M_; m += 256)
            s += RATIO_ * (emx * S_u[bh * M_ + m] + EPS_ * (float)N_);
        red[tid] = s;
    }
    __syncthreads();
    for (int s = 128; s > 0; s >>= 1) {
        if (tid < s) red[tid] += red[tid + s];
        __syncthreads();
    }
    if (tid == 0) kss[bh] = red[0];
}

// ---------------- query side, single pass over M (max-free rescaling) ----------------
// out_row = (SUM_m u_m*ctx[m,:] + EPS*e^{mx}*Cs) / (SUM_m u_m*ks[m] + EPS*e^{mx}*kss),  u = exp(td - diag)
// grid: x = N/64 (64 rows per block), y = bh
__global__ __launch_bounds__(256) void qattn(
    const float* __restrict__ Q, const float* __restrict__ proj,
    const float* __restrict__ ksum_f, const float* __restrict__ ctx_f,
    const float* __restrict__ Cs, const float* __restrict__ kss,
    float* __restrict__ attn)
{
    __shared__ float QsT[64][68];   // [d][r]
    __shared__ float buf[64][68];   // projT [d][mm] (phase 1), then ctx [mm][dh] (phase 2)
    __shared__ float Us[64][68];    // u values [r][mm]
    __shared__ float ks[MP_];
    __shared__ float diag[64];
    __shared__ float red[256];

    int bh = blockIdx.y;
    int b = bh >> 4, h = bh & 15;
    int n0 = blockIdx.x * 64;
    int tid = threadIdx.x;
    int rq = tid >> 4;   // rows rq*4 .. +3
    int mq = tid & 15;   // m (phase1) / dh (phase2): mq*4 .. +3

    #pragma unroll
    for (int l = 0; l < 4; ++l) {
        int idx = tid + 256 * l;
        int r = idx >> 4;
        int d4 = (idx & 15) * 4;
        const float4 qv = *(const float4*)(Q + ((size_t)(b * N_ + n0 + r)) * D_ + h * DH_ + d4);
        QsT[d4 + 0][r] = qv.x; QsT[d4 + 1][r] = qv.y;
        QsT[d4 + 2][r] = qv.z; QsT[d4 + 3][r] = qv.w;
    }
    for (int m = tid; m < MP_; m += 256) ks[m] = ksum_f[bh * MP_ + m];
    __syncthreads();
    {
        int r = tid & 63, part = tid >> 6;
        float s = 0.f;
        #pragma unroll
        for (int dd = 0; dd < 16; ++dd) {
            float v = QsT[part * 16 + dd][r];
            s = fmaf(v, v, s);
        }
        red[tid] = s;
    }
    __syncthreads();
    if (tid < 64) diag[tid] = (red[tid] + red[tid + 64] + red[tid + 128] + red[tid + 192]) * 0.0625f;
    __syncthreads();

    float oacc[4][4];
    #pragma unroll
    for (int i = 0; i < 4; ++i)
        #pragma unroll
        for (int j = 0; j < 4; ++j) oacc[i][j] = 0.f;
    float dacc[4] = {0.f, 0.f, 0.f, 0.f};
    float tmax[4] = {-1e30f, -1e30f, -1e30f, -1e30f};

    for (int c = 0; c < 5; ++c) {
        int mbase = c * 64;
        // stage projT chunk: buf[d][mm]
        for (int i = tid; i < 64 * 64; i += 256) {
            int mm = i & 63, d = i >> 6;
            int mg = mbase + mm;
            buf[d][mm] = (mg < M_) ? proj[mg * 64 + d] : 0.f;
        }
        __syncthreads();
        // phase 1: td = (q*dn) @ projT
        float td[4][4];
        #pragma unroll
        for (int i = 0; i < 4; ++i)
            #pragma unroll
            for (int j = 0; j < 4; ++j) td[i][j] = 0.f;
        #pragma unroll 4
        for (int d = 0; d < 64; ++d) {
            const float4 qv = *(const float4*)&QsT[d][rq * 4];
            const float4 pv = *(const float4*)&buf[d][mq * 4];
            float qa[4] = {qv.x, qv.y, qv.z, qv.w};
            float pa[4] = {pv.x, pv.y, pv.z, pv.w};
            #pragma unroll
            for (int i = 0; i < 4; ++i)
                #pragma unroll
                for (int j = 0; j < 4; ++j)
                    td[i][j] = fmaf(qa[i], pa[j], td[i][j]);
        }
        #pragma unroll
        for (int i = 0; i < 4; ++i) {
            float dg = diag[rq * 4 + i];
            float4 uv;
            float uarr[4];
            #pragma unroll
            for (int j = 0; j < 4; ++j) {
                int mg = mbase + mq * 4 + j;
                float t = td[i][j] * DN_;
                if (mg < M_) tmax[i] = fmaxf(tmax[i], t);
                float u = expf(t - dg);
                uarr[j] = u;
                dacc[i] = fmaf(u, ks[mg], dacc[i]);   // ks[mg]=0 for mg>=M_
            }
            uv.x = uarr[0]; uv.y = uarr[1]; uv.z = uarr[2]; uv.w = uarr[3];
            *(float4*)&Us[rq * 4 + i][mq * 4] = uv;
        }
        __syncthreads();
        // stage ctx chunk: buf[mm][dh]  (ctx_f zero-padded to MP_ rows)
        #pragma unroll
        for (int l = 0; l < 4; ++l) {
            int idx = tid + 256 * l;
            int mrow = idx >> 4;
            int dh4 = (idx & 15) * 4;
            const float4 cv = *(const float4*)(ctx_f + ((size_t)bh * MP_ + mbase + mrow) * 64 + dh4);
            *(float4*)&buf[mrow][dh4] = cv;
        }
        __syncthreads();
        // phase 2: oacc += u @ ctx
        for (int m = 0; m < 64; ++m) {
            float u0 = Us[rq * 4 + 0][m];
            float u1 = Us[rq * 4 + 1][m];
            float u2 = Us[rq * 4 + 2][m];
            float u3 = Us[rq * 4 + 3][m];
            const float4 cv = *(const float4*)&buf[m][mq * 4];
            float ca[4] = {cv.x, cv.y, cv.z, cv.w};
            #pragma unroll
            for (int j = 0; j < 4; ++j) {
                oacc[0][j] = fmaf(u0, ca[j], oacc[0][j]);
                oacc[1][j] = fmaf(u1, ca[j], oacc[1][j]);
                oacc[2][j] = fmaf(u2, ca[j], oacc[2][j]);
                oacc[3][j] = fmaf(u3, ca[j], oacc[3][j]);
            }
        }
        __syncthreads();
    }
    // reduce tmax/dacc across the 16 mq lanes (width-16 segments)
    #pragma unroll
    for (int i = 0; i < 4; ++i) {
        #pragma unroll
        for (int o = 8; o > 0; o >>= 1) {
            tmax[i] = fmaxf(tmax[i], __shfl_xor(tmax[i], o, 16));
            dacc[i] += __shfl_xor(dacc[i], o, 16);
        }
    }
    float kssv = kss[bh];
    const float4 cs4 = *(const float4*)(Cs + bh * 64 + mq * 4);
    float csa[4] = {cs4.x, cs4.y, cs4.z, cs4.w};
    #pragma unroll
    for (int i = 0; i < 4; ++i) {
        float fac = EPS_ * expf(tmax[i]);
        float di = 1.f / (dacc[i] + fac * kssv);
        float4 o;
        o.x = (oacc[i][0] + fac * csa[0]) * di;
        o.y = (oacc[i][1] + fac * csa[1]) * di;
        o.z = (oacc[i][2] + fac * csa[2]) * di;
        o.w = (oacc[i][3] + fac * csa[3]) * di;
        int r = n0 + rq * 4 + i;
        *(float4*)(attn + ((size_t)(b * N_ + r)) * D_ + h * DH_ + mq * 4) = o;
    }
}

// ---------------- launch ----------------
extern "C" void kernel_launch(void* const* d_in, const int* in_sizes, int n_in,
                              void* d_out, int out_size, void* d_ws, size_t ws_size,
                              hipStream_t stream)
{
    const float* x    = (const float*)d_in[0];
    const float* Wq   = (const float*)d_in[1];
    const float* bq   = (const float*)d_in[2];
    const float* Wk   = (const float*)d_in[3];
    const float* bk   = (const float*)d_in[4];
    const float* Wv   = (const float*)d_in[5];
    const float* bv   = (const float*)d_in[6];
    const float* Wo   = (const float*)d_in[7];
    const float* bo   = (const float*)d_in[8];
    const float* Wfc  = (const float*)d_in[9];
    const float* bfc  = (const float*)d_in[10];
    const float* proj = (const float*)d_in[11];
    float* out = (float*)d_out;

    float* ws = (float*)d_ws;
    const size_t nTok = (size_t)B_ * N_ * D_;       // 16,777,216
    const size_t nSu  = 64 * M_;
    const size_t nCu  = (size_t)64 * M_ * 64;
    const size_t nVs  = 64 * 64;
    const size_t nMx  = 64;
    const size_t nKsf = 64 * MP_;
    const size_t nCtx = (size_t)64 * MP_ * 64;
    const size_t nCs  = 64 * 64;

    const size_t offQ   = 0;
    const size_t offK   = nTok;
    const size_t offV   = nTok * 2;
    const size_t offSu  = nTok * 3;
    const size_t offCu  = offSu + nSu;
    const size_t offVs  = offCu + nCu;
    const size_t offMx  = offVs + nVs;
    const size_t offKsf = offMx + nMx;
    const size_t offCtx = offKsf + nKsf;
    const size_t offCs  = offCtx + nCtx;
    const size_t offKss = offCs + nCs;

    float* Q    = ws + offQ;
    float* Kb   = ws + offK;
    float* Vb   = ws + offV;
    float* S_u  = ws + offSu;
    float* C_u  = ws + offCu;
    float* Vsum = ws + offVs;
    unsigned* mx = (unsigned*)(ws + offMx);
    float* ksf  = ws + offKsf;
    float* ctxf = ws + offCtx;
    float* Cs   = ws + offCs;
    float* kss  = ws + offKss;
    float* attn = Kb;   // K dead after kside
    float* hbuf = Vb;   // V dead after kside

    int nzero = (int)(nSu + nCu + nVs + nMx);
    zero_kernel<<<dim3((nzero + 255) / 256), dim3(256), 0, stream>>>(S_u, nzero);

    dim3 gg(D_ / BN, (B_ * N_) / BM);   // 16 x 128
    gemm_nt<<<gg, dim3(256), 0, stream>>>(x, Wq, bq, Q, D_, D_, 0);
    gemm_nt<<<gg, dim3(256), 0, stream>>>(x, Wk, bk, Kb, D_, D_, 0);
    gemm_nt<<<gg, dim3(256), 0, stream>>>(x, Wv, bv, Vb, D_, D_, 0);

    kside<<<dim3(8, 5, 64), dim3(256), 0, stream>>>(Kb, Vb, proj, S_u, C_u, Vsum, mx);
    finalize_kernel<<<dim3(64), dim3(256), 0, stream>>>(S_u, C_u, Vsum, mx, ksf, ctxf, Cs, kss);
    qattn<<<dim3(N_ / 64, 64), dim3(256), 0, stream>>>(Q, proj, ksf, ctxf, Cs, kss, attn);

    gemm_nt<<<gg, dim3(256), 0, stream>>>(attn, Wo, bo, hbuf, D_, D_, 0);
    gemm_nt<<<gg, dim3(256), 0, stream>>>(hbuf, Wfc, bfc, out, D_, D_, 1);
}

// Round 4
// 1565.070 us; speedup vs baseline: 11.6159x; 2.0079x over previous
//
#include <hip/hip_runtime.h>
#include <math.h>

#define B_ 4
#define N_ 4096
#define D_ 1024
#define H_ 16
#define DH_ 64
#define M_ 266
#define MP_ 320   // M padded to 5 chunks of 64 (qattn iterates 5*64)

#define DN_ 0.35355339059327373f      // 64^-0.25
#define RATIO_ 0.06131393394849658f   // 266^-0.5
#define EPS_ 1e-4f

typedef __attribute__((ext_vector_type(8))) short bfrag;   // 8 bf16 = 4 VGPRs
typedef __attribute__((ext_vector_type(4))) float f4;

// ---------- ordered-uint encoding for float atomicMax ----------
__device__ __forceinline__ unsigned f2ord(float f) {
    unsigned u = __float_as_uint(f);
    return (u & 0x80000000u) ? ~u : (u | 0x80000000u);
}
__device__ __forceinline__ float ord2f(unsigned u) {
    unsigned b = (u & 0x80000000u) ? (u & 0x7fffffffu) : ~u;
    return __uint_as_float(b);
}

__global__ void zero_kernel(float* __restrict__ p, int n) {
    int i = blockIdx.x * 256 + threadIdx.x;
    if (i < n) p[i] = 0.f;
}

// split fp32 -> bf16 hi (truncate) + bf16 lo (truncated residual); pack 2 at a time
__device__ __forceinline__ void split2pack(float x, float y, unsigned* hp, unsigned* lp) {
    unsigned ux = __float_as_uint(x), uy = __float_as_uint(y);
    float hx = __uint_as_float(ux & 0xffff0000u);
    float hy = __uint_as_float(uy & 0xffff0000u);
    float lx = x - hx, ly = y - hy;   // exact residuals
    *hp = (ux >> 16) | (uy & 0xffff0000u);
    *lp = (__float_as_uint(lx) >> 16) | (__float_as_uint(ly) & 0xffff0000u);
}

// ---------------- split-bf16 3-product MFMA GEMM: C[M,1024] = A[M,K] @ B[1024,K]^T + bias ----------------
// 128x128 tile, BK=32, 4 waves in 2x2, each wave 64x64 via 4x4 16x16x32 MFMAs x 3 products.
__global__ __launch_bounds__(256) void gemm3_nt(const float* __restrict__ A,
        const float* __restrict__ Bw, const float* __restrict__ bias,
        float* __restrict__ C, int Kdim, int Ncols, int relu)
{
    __shared__ __align__(16) unsigned short Ah[128 * 32];
    __shared__ __align__(16) unsigned short Al[128 * 32];
    __shared__ __align__(16) unsigned short Bh[128 * 32];
    __shared__ __align__(16) unsigned short Bl[128 * 32];

    int tid = threadIdx.x;
    int bm = blockIdx.y * 128;
    int bn = blockIdx.x * 128;
    int lane = tid & 63;
    int wv = tid >> 6;
    int wm = wv >> 1, wn = wv & 1;
    int ml = lane & 15, kq = lane >> 4;

    f4 acc[4][4];
    #pragma unroll
    for (int i = 0; i < 4; ++i)
        #pragma unroll
        for (int j = 0; j < 4; ++j)
            acc[i][j] = (f4){0.f, 0.f, 0.f, 0.f};

    for (int kt = 0; kt < Kdim; kt += 32) {
        __syncthreads();   // protect previous iteration's fragment reads
        #pragma unroll
        for (int j = 0; j < 4; ++j) {
            int c = tid + 256 * j;          // 1024 float4 chunks = 128 rows x 8
            int m = c >> 3, k4 = c & 7;
            int li = m * 32 + k4 * 4;       // ushort index; byte addr = c*8 -> stride-1 b64 writes
            unsigned h0, l0, h1, l1;
            const float4 a = *(const float4*)(A + (size_t)(bm + m) * Kdim + kt + k4 * 4);
            split2pack(a.x, a.y, &h0, &l0);
            split2pack(a.z, a.w, &h1, &l1);
            *(uint2*)&Ah[li] = make_uint2(h0, h1);
            *(uint2*)&Al[li] = make_uint2(l0, l1);
            const float4 b = *(const float4*)(Bw + (size_t)(bn + m) * Kdim + kt + k4 * 4);
            split2pack(b.x, b.y, &h0, &l0);
            split2pack(b.z, b.w, &h1, &l1);
            *(uint2*)&Bh[li] = make_uint2(h0, h1);
            *(uint2*)&Bl[li] = make_uint2(l0, l1);
        }
        __syncthreads();
        bfrag ah[4], al[4], bh[4], bl[4];
        #pragma unroll
        for (int i = 0; i < 4; ++i) {
            int arow = wm * 64 + i * 16 + ml;
            ah[i] = *(const bfrag*)&Ah[arow * 32 + kq * 8];
            al[i] = *(const bfrag*)&Al[arow * 32 + kq * 8];
            int brow = wn * 64 + i * 16 + ml;
            bh[i] = *(const bfrag*)&Bh[brow * 32 + kq * 8];
            bl[i] = *(const bfrag*)&Bl[brow * 32 + kq * 8];
        }
        #pragma unroll
        for (int mi = 0; mi < 4; ++mi)
            #pragma unroll
            for (int ni = 0; ni < 4; ++ni) {
                acc[mi][ni] = __builtin_amdgcn_mfma_f32_16x16x32_bf16(ah[mi], bh[ni], acc[mi][ni], 0, 0, 0);
                acc[mi][ni] = __builtin_amdgcn_mfma_f32_16x16x32_bf16(al[mi], bh[ni], acc[mi][ni], 0, 0, 0);
                acc[mi][ni] = __builtin_amdgcn_mfma_f32_16x16x32_bf16(ah[mi], bl[ni], acc[mi][ni], 0, 0, 0);
            }
    }
    // epilogue: C/D layout col=lane&15, row=(lane>>4)*4+reg
    #pragma unroll
    for (int ni = 0; ni < 4; ++ni) {
        int col = bn + wn * 64 + ni * 16 + ml;
        float bv = bias[col];
        #pragma unroll
        for (int mi = 0; mi < 4; ++mi) {
            int row0 = bm + wm * 64 + mi * 16 + kq * 4;
            #pragma unroll
            for (int r = 0; r < 4; ++r) {
                float o = acc[mi][ni][r] + bv;
                if (relu) o = fmaxf(o, 0.f);
                C[(size_t)(row0 + r) * Ncols + col] = o;
            }
        }
    }
}

// ---------------- key side: S_u[m]=SUM exp(td-diag), C_u[m,dh]=SUM exp()*v, Vsum[dh], max(td) ----------------
// grid: x = nsplit(8, 512 rows each), y = mtile(5, 64 wide), z = bh(64)
__global__ __launch_bounds__(256) void kside(
    const float* __restrict__ Kin, const float* __restrict__ Vin,
    const float* __restrict__ proj,
    float* __restrict__ S_u, float* __restrict__ C_u,
    float* __restrict__ Vsum, unsigned int* __restrict__ mxp)
{
    int bh = blockIdx.z;
    int b = bh >> 4, h = bh & 15;
    int m0 = blockIdx.y * 64;
    int mwidth = min(64, M_ - m0);
    int n0 = blockIdx.x * 512;
    int tid = threadIdx.x;

    __shared__ float projT[64][68];   // [d][mm]
    __shared__ float KsT[64][34];     // [d][r]
    __shared__ float Vs[32][68];      // [r][dh]
    __shared__ float Ss[32][68];      // [r][mm]
    __shared__ float diag[32];
    __shared__ float red[256];

    for (int i = tid; i < 64 * 64; i += 256) {
        int mm = i >> 6, d = i & 63;
        projT[d][mm] = (mm < mwidth) ? proj[(m0 + mm) * 64 + d] : 0.f;
    }

    int rq = tid >> 4;
    int mq = tid & 15;
    int tm = tid & 15;
    int tdh = tid >> 4;
    bool isMT0 = (blockIdx.y == 0);

    float cacc[4][4];
    #pragma unroll
    for (int i = 0; i < 4; ++i)
        #pragma unroll
        for (int j = 0; j < 4; ++j) cacc[i][j] = 0.f;
    float vsum[4] = {0.f, 0.f, 0.f, 0.f};
    float ksum[4] = {0.f, 0.f, 0.f, 0.f};
    float lmax = -1e30f;
    bool mvalid[4];
    #pragma unroll
    for (int j = 0; j < 4; ++j) mvalid[j] = (mq * 4 + j) < mwidth;

    for (int nc = 0; nc < 512; nc += 32) {
        __syncthreads();
        #pragma unroll
        for (int l = 0; l < 2; ++l) {
            int idx = tid + 256 * l;
            int r = idx >> 4;
            int d4 = (idx & 15) * 4;
            size_t gro = ((size_t)(b * N_ + n0 + nc + r)) * D_ + h * DH_ + d4;
            const float4 kv = *(const float4*)(Kin + gro);
            KsT[d4 + 0][r] = kv.x; KsT[d4 + 1][r] = kv.y;
            KsT[d4 + 2][r] = kv.z; KsT[d4 + 3][r] = kv.w;
            const float4 vv = *(const float4*)(Vin + gro);
            *(float4*)&Vs[r][d4] = vv;
        }
        __syncthreads();
        {
            int r = tid & 31, part = tid >> 5;
            float s = 0.f;
            #pragma unroll
            for (int dd = 0; dd < 8; ++dd) {
                float kv = KsT[part * 8 + dd][r];
                s = fmaf(kv, kv, s);
            }
            red[tid] = s;
        }
        __syncthreads();
        if (tid < 32) {
            float s = 0.f;
            #pragma unroll
            for (int p = 0; p < 8; ++p) s += red[tid + 32 * p];
            diag[tid] = s * 0.0625f;
        }
        __syncthreads();
        float td[2][4];
        #pragma unroll
        for (int i = 0; i < 2; ++i)
            #pragma unroll
            for (int j = 0; j < 4; ++j) td[i][j] = 0.f;
        #pragma unroll 8
        for (int d = 0; d < 64; ++d) {
            const float2 kk = *(const float2*)&KsT[d][rq * 2];
            const float4 p4 = *(const float4*)&projT[d][mq * 4];
            float pv[4] = {p4.x, p4.y, p4.z, p4.w};
            #pragma unroll
            for (int j = 0; j < 4; ++j) {
                td[0][j] = fmaf(kk.x, pv[j], td[0][j]);
                td[1][j] = fmaf(kk.y, pv[j], td[1][j]);
            }
        }
        #pragma unroll
        for (int i = 0; i < 2; ++i) {
            int r = rq * 2 + i;
            float dg = diag[r];
            #pragma unroll
            for (int j = 0; j < 4; ++j) {
                float t = td[i][j] * DN_;
                float s = 0.f;
                if (mvalid[j]) {
                    lmax = fmaxf(lmax, t);
                    s = expf(t - dg);
                }
                Ss[r][mq * 4 + j] = s;
                ksum[j] += s;
            }
        }
        __syncthreads();
        for (int r = 0; r < 32; ++r) {
            const float4 s4 = *(const float4*)&Ss[r][tm * 4];
            const float4 v4 = *(const float4*)&Vs[r][tdh * 4];
            float sv[4] = {s4.x, s4.y, s4.z, s4.w};
            float vv[4] = {v4.x, v4.y, v4.z, v4.w};
            #pragma unroll
            for (int i = 0; i < 4; ++i)
                #pragma unroll
                for (int j = 0; j < 4; ++j)
                    cacc[i][j] = fmaf(sv[i], vv[j], cacc[i][j]);
            if (isMT0 && tm == 0) {
                #pragma unroll
                for (int j = 0; j < 4; ++j) vsum[j] += vv[j];
            }
        }
    }
    for (int j = 0; j < 4; ++j) {
        __syncthreads();
        red[tid] = ksum[j];
        __syncthreads();
        if (tid < 16) {
            float s = 0.f;
            #pragma unroll
            for (int q = 0; q < 16; ++q) s += red[q * 16 + tid];
            if (tid * 4 + j < mwidth)
                atomicAdd(S_u + bh * M_ + m0 + tid * 4 + j, s);
        }
    }
    __syncthreads();
    red[tid] = lmax;
    __syncthreads();
    for (int s = 128; s > 0; s >>= 1) {
        if (tid < s) red[tid] = fmaxf(red[tid], red[tid + s]);
        __syncthreads();
    }
    if (tid == 0) atomicMax(mxp + bh, f2ord(red[0]));
    #pragma unroll
    for (int i = 0; i < 4; ++i) {
        int m = tm * 4 + i;
        if (m < mwidth) {
            #pragma unroll
            for (int j = 0; j < 4; ++j)
                atomicAdd(C_u + ((size_t)bh * M_ + m0 + m) * 64 + tdh * 4 + j, cacc[i][j]);
        }
    }
    if (isMT0 && tm == 0) {
        #pragma unroll
        for (int j = 0; j < 4; ++j)
            atomicAdd(Vsum + bh * 64 + tdh * 4 + j, vsum[j]);
    }
}

// ---------------- finalize: ctx (zero-padded to MP_ rows), ks (padded), Cs = sum_m ctx, kss = sum_m ks ----------------
__global__ __launch_bounds__(256) void finalize_kernel(
    const float* __restrict__ S_u, const float* __restrict__ C_u,
    const float* __restrict__ Vsum, const unsigned* __restrict__ mxp,
    float* __restrict__ ksum_f, float* __restrict__ ctx_f,
    float* __restrict__ Cs, float* __restrict__ kss)
{
    __shared__ float red[256];
    int bh = blockIdx.x;
    int tid = threadIdx.x;
    float emx = expf(-ord2f(mxp[bh]));
    for (int i = tid; i < MP_ * 64; i += 256) {
        int m = i >> 6, dh = i & 63;
        float v = 0.f;
        if (m < M_)
            v = RATIO_ * (emx * C_u[((size_t)bh * M_ + m) * 64 + dh] + EPS_ * Vsum[bh * 64 + dh]);
        ctx_f[(size_t)bh * MP_ * 64 + i] = v;
    }
    for (int m = tid; m < MP_; m += 256)
        ksum_f[bh * MP_ + m] = (m < M_) ? RATIO_ * (emx * S_u[bh * M_ + m] + EPS_ * (float)N_) : 0.f;

    {
        int dh = tid & 63, part = tid >> 6;
        float s = 0.f;
        for (int m = part; m < M_; m += 4)
            s += RATIO_ * (emx * C_u[((size_t)bh * M_ + m) * 64 + dh] + EPS_ * Vsum[bh * 64 + dh]);
        red[tid] = s;
    }
    __syncthreads();
    if (tid < 64) Cs[bh * 64 + tid] = red[tid] + red[tid + 64] + red[tid + 128] + red[tid + 192];
    __syncthreads();
    {
        float s = 0.f;
        for (int m = tid; m < M_; m += 256)
            s += RATIO_ * (emx * S_u[bh * M_ + m] + EPS_ * (float)N_);
        red[tid] = s;
    }
    __syncthreads();
    for (int s = 128; s > 0; s >>= 1) {
        if (tid < s) red[tid] += red[tid + s];
        __syncthreads();
    }
    if (tid == 0) kss[bh] = red[0];
}

// ---------------- query side, single pass over M (max-free rescaling) ----------------
__global__ __launch_bounds__(256) void qattn(
    const float* __restrict__ Q, const float* __restrict__ proj,
    const float* __restrict__ ksum_f, const float* __restrict__ ctx_f,
    const float* __restrict__ Cs, const float* __restrict__ kss,
    float* __restrict__ attn)
{
    __shared__ float QsT[64][68];   // [d][r]
    __shared__ float buf[64][68];   // projT [d][mm] (phase 1), then ctx [mm][dh] (phase 2)
    __shared__ float Us[64][68];    // u values [r][mm]
    __shared__ float ks[MP_];
    __shared__ float diag[64];
    __shared__ float red[256];

    int bh = blockIdx.y;
    int b = bh >> 4, h = bh & 15;
    int n0 = blockIdx.x * 64;
    int tid = threadIdx.x;
    int rq = tid >> 4;   // rows rq*4 .. +3
    int mq = tid & 15;   // m (phase1) / dh (phase2): mq*4 .. +3

    #pragma unroll
    for (int l = 0; l < 4; ++l) {
        int idx = tid + 256 * l;
        int r = idx >> 4;
        int d4 = (idx & 15) * 4;
        const float4 qv = *(const float4*)(Q + ((size_t)(b * N_ + n0 + r)) * D_ + h * DH_ + d4);
        QsT[d4 + 0][r] = qv.x; QsT[d4 + 1][r] = qv.y;
        QsT[d4 + 2][r] = qv.z; QsT[d4 + 3][r] = qv.w;
    }
    for (int m = tid; m < MP_; m += 256) ks[m] = ksum_f[bh * MP_ + m];
    __syncthreads();
    {
        int r = tid & 63, part = tid >> 6;
        float s = 0.f;
        #pragma unroll
        for (int dd = 0; dd < 16; ++dd) {
            float v = QsT[part * 16 + dd][r];
            s = fmaf(v, v, s);
        }
        red[tid] = s;
    }
    __syncthreads();
    if (tid < 64) diag[tid] = (red[tid] + red[tid + 64] + red[tid + 128] + red[tid + 192]) * 0.0625f;
    __syncthreads();

    float oacc[4][4];
    #pragma unroll
    for (int i = 0; i < 4; ++i)
        #pragma unroll
        for (int j = 0; j < 4; ++j) oacc[i][j] = 0.f;
    float dacc[4] = {0.f, 0.f, 0.f, 0.f};
    float tmax[4] = {-1e30f, -1e30f, -1e30f, -1e30f};

    for (int c = 0; c < 5; ++c) {
        int mbase = c * 64;
        for (int i = tid; i < 64 * 64; i += 256) {
            int mm = i & 63, d = i >> 6;
            int mg = mbase + mm;
            buf[d][mm] = (mg < M_) ? proj[mg * 64 + d] : 0.f;
        }
        __syncthreads();
        float td[4][4];
        #pragma unroll
        for (int i = 0; i < 4; ++i)
            #pragma unroll
            for (int j = 0; j < 4; ++j) td[i][j] = 0.f;
        #pragma unroll 4
        for (int d = 0; d < 64; ++d) {
            const float4 qv = *(const float4*)&QsT[d][rq * 4];
            const float4 pv = *(const float4*)&buf[d][mq * 4];
            float qa[4] = {qv.x, qv.y, qv.z, qv.w};
            float pa[4] = {pv.x, pv.y, pv.z, pv.w};
            #pragma unroll
            for (int i = 0; i < 4; ++i)
                #pragma unroll
                for (int j = 0; j < 4; ++j)
                    td[i][j] = fmaf(qa[i], pa[j], td[i][j]);
        }
        #pragma unroll
        for (int i = 0; i < 4; ++i) {
            float dg = diag[rq * 4 + i];
            float4 uv;
            float uarr[4];
            #pragma unroll
            for (int j = 0; j < 4; ++j) {
                int mg = mbase + mq * 4 + j;
                float t = td[i][j] * DN_;
                if (mg < M_) tmax[i] = fmaxf(tmax[i], t);
                float u = expf(t - dg);
                uarr[j] = u;
                dacc[i] = fmaf(u, ks[mg], dacc[i]);   // ks[mg]=0 for mg>=M_
            }
            uv.x = uarr[0]; uv.y = uarr[1]; uv.z = uarr[2]; uv.w = uarr[3];
            *(float4*)&Us[rq * 4 + i][mq * 4] = uv;
        }
        __syncthreads();
        #pragma unroll
        for (int l = 0; l < 4; ++l) {
            int idx = tid + 256 * l;
            int mrow = idx >> 4;
            int dh4 = (idx & 15) * 4;
            const float4 cv = *(const float4*)(ctx_f + ((size_t)bh * MP_ + mbase + mrow) * 64 + dh4);
            *(float4*)&buf[mrow][dh4] = cv;
        }
        __syncthreads();
        for (int m = 0; m < 64; ++m) {
            float u0 = Us[rq * 4 + 0][m];
            float u1 = Us[rq * 4 + 1][m];
            float u2 = Us[rq * 4 + 2][m];
            float u3 = Us[rq * 4 + 3][m];
            const float4 cv = *(const float4*)&buf[m][mq * 4];
            float ca[4] = {cv.x, cv.y, cv.z, cv.w};
            #pragma unroll
            for (int j = 0; j < 4; ++j) {
                oacc[0][j] = fmaf(u0, ca[j], oacc[0][j]);
                oacc[1][j] = fmaf(u1, ca[j], oacc[1][j]);
                oacc[2][j] = fmaf(u2, ca[j], oacc[2][j]);
                oacc[3][j] = fmaf(u3, ca[j], oacc[3][j]);
            }
        }
        __syncthreads();
    }
    #pragma unroll
    for (int i = 0; i < 4; ++i) {
        #pragma unroll
        for (int o = 8; o > 0; o >>= 1) {
            tmax[i] = fmaxf(tmax[i], __shfl_xor(tmax[i], o, 16));
            dacc[i] += __shfl_xor(dacc[i], o, 16);
        }
    }
    float kssv = kss[bh];
    const float4 cs4 = *(const float4*)(Cs + bh * 64 + mq * 4);
    float csa[4] = {cs4.x, cs4.y, cs4.z, cs4.w};
    #pragma unroll
    for (int i = 0; i < 4; ++i) {
        float fac = EPS_ * expf(tmax[i]);
        float di = 1.f / (dacc[i] + fac * kssv);
        float4 o;
        o.x = (oacc[i][0] + fac * csa[0]) * di;
        o.y = (oacc[i][1] + fac * csa[1]) * di;
        o.z = (oacc[i][2] + fac * csa[2]) * di;
        o.w = (oacc[i][3] + fac * csa[3]) * di;
        int r = n0 + rq * 4 + i;
        *(float4*)(attn + ((size_t)(b * N_ + r)) * D_ + h * DH_ + mq * 4) = o;
    }
}

// ---------------- launch ----------------
extern "C" void kernel_launch(void* const* d_in, const int* in_sizes, int n_in,
                              void* d_out, int out_size, void* d_ws, size_t ws_size,
                              hipStream_t stream)
{
    const float* x    = (const float*)d_in[0];
    const float* Wq   = (const float*)d_in[1];
    const float* bq   = (const float*)d_in[2];
    const float* Wk   = (const float*)d_in[3];
    const float* bk   = (const float*)d_in[4];
    const float* Wv   = (const float*)d_in[5];
    const float* bv   = (const float*)d_in[6];
    const float* Wo   = (const float*)d_in[7];
    const float* bo   = (const float*)d_in[8];
    const float* Wfc  = (const float*)d_in[9];
    const float* bfc  = (const float*)d_in[10];
    const float* proj = (const float*)d_in[11];
    float* out = (float*)d_out;

    float* ws = (float*)d_ws;
    const size_t nTok = (size_t)B_ * N_ * D_;       // 16,777,216
    const size_t nSu  = 64 * M_;
    const size_t nCu  = (size_t)64 * M_ * 64;
    const size_t nVs  = 64 * 64;
    const size_t nMx  = 64;
    const size_t nKsf = 64 * MP_;
    const size_t nCtx = (size_t)64 * MP_ * 64;
    const size_t nCs  = 64 * 64;

    const size_t offQ   = 0;
    const size_t offK   = nTok;
    const size_t offV   = nTok * 2;
    const size_t offSu  = nTok * 3;
    const size_t offCu  = offSu + nSu;
    const size_t offVs  = offCu + nCu;
    const size_t offMx  = offVs + nVs;
    const size_t offKsf = offMx + nMx;
    const size_t offCtx = offKsf + nKsf;
    const size_t offCs  = offCtx + nCtx;
    const size_t offKss = offCs + nCs;

    float* Q    = ws + offQ;
    float* Kb   = ws + offK;
    float* Vb   = ws + offV;
    float* S_u  = ws + offSu;
    float* C_u  = ws + offCu;
    float* Vsum = ws + offVs;
    unsigned* mx = (unsigned*)(ws + offMx);
    float* ksf  = ws + offKsf;
    float* ctxf = ws + offCtx;
    float* Cs   = ws + offCs;
    float* kss  = ws + offKss;
    float* attn = Kb;   // K dead after kside
    float* hbuf = Vb;   // V dead after kside

    int nzero = (int)(nSu + nCu + nVs + nMx);
    zero_kernel<<<dim3((nzero + 255) / 256), dim3(256), 0, stream>>>(S_u, nzero);

    dim3 gg(D_ / 128, (B_ * N_) / 128);   // 8 x 128
    gemm3_nt<<<gg, dim3(256), 0, stream>>>(x, Wq, bq, Q, D_, D_, 0);
    gemm3_nt<<<gg, dim3(256), 0, stream>>>(x, Wk, bk, Kb, D_, D_, 0);
    gemm3_nt<<<gg, dim3(256), 0, stream>>>(x, Wv, bv, Vb, D_, D_, 0);

    kside<<<dim3(8, 5, 64), dim3(256), 0, stream>>>(Kb, Vb, proj, S_u, C_u, Vsum, mx);
    finalize_kernel<<<dim3(64), dim3(256), 0, stream>>>(S_u, C_u, Vsum, mx, ksf, ctxf, Cs, kss);
    qattn<<<dim3(N_ / 64, 64), dim3(256), 0, stream>>>(Q, proj, ksf, ctxf, Cs, kss, attn);

    gemm3_nt<<<gg, dim3(256), 0, stream>>>(attn, Wo, bo, hbuf, D_, D_, 0);
    gemm3_nt<<<gg, dim3(256), 0, stream>>>(hbuf, Wfc, bfc, out, D_, D_, 1);
}

// Round 5
// 1255.692 us; speedup vs baseline: 14.4778x; 1.2464x over previous
//
#include <hip/hip_runtime.h>
#include <math.h>

#define B_ 4
#define N_ 4096
#define D_ 1024
#define H_ 16
#define DH_ 64
#define M_ 266
#define MP_ 320   // M padded to 5 chunks of 64

#define DN_ 0.35355339059327373f      // 64^-0.25
#define RATIO_ 0.06131393394849658f   // 266^-0.5
#define EPS_ 1e-4f
#define KP_ 72    // ushort row stride (144B): b128 frag reads get contiguous-class bank spread

typedef __attribute__((ext_vector_type(8))) short bfrag;   // 8 bf16 = 4 VGPRs
typedef __attribute__((ext_vector_type(4))) float f4;

// ---------- ordered-uint encoding for float atomicMax ----------
__device__ __forceinline__ unsigned f2ord(float f) {
    unsigned u = __float_as_uint(f);
    return (u & 0x80000000u) ? ~u : (u | 0x80000000u);
}
__device__ __forceinline__ float ord2f(unsigned u) {
    unsigned b = (u & 0x80000000u) ? (u & 0x7fffffffu) : ~u;
    return __uint_as_float(b);
}

__global__ void zero_kernel(float* __restrict__ p, int n) {
    int i = blockIdx.x * 256 + threadIdx.x;
    if (i < n) p[i] = 0.f;
}

// split fp32 -> bf16 hi (truncate) + bf16 lo (truncated residual); pack 2 at a time
__device__ __forceinline__ void split2pack(float x, float y, unsigned* hp, unsigned* lp) {
    unsigned ux = __float_as_uint(x), uy = __float_as_uint(y);
    float hx = __uint_as_float(ux & 0xffff0000u);
    float hy = __uint_as_float(uy & 0xffff0000u);
    float lx = x - hx, ly = y - hy;
    *hp = (ux >> 16) | (uy & 0xffff0000u);
    *lp = (__float_as_uint(lx) >> 16) | (__float_as_uint(ly) & 0xffff0000u);
}
// round-to-nearest-even bf16 (unbiased — needed for single-bf16 operands)
__device__ __forceinline__ unsigned short bf16rne(float x) {
    unsigned u = __float_as_uint(x);
    return (unsigned short)((u + 0x7fffu + ((u >> 16) & 1u)) >> 16);
}

// ---------------- split-bf16 3-product MFMA GEMM (unchanged from round 4) ----------------
__global__ __launch_bounds__(256) void gemm3_nt(const float* __restrict__ A,
        const float* __restrict__ Bw, const float* __restrict__ bias,
        float* __restrict__ C, int Kdim, int Ncols, int relu)
{
    __shared__ __align__(16) unsigned short Ah[128 * 32];
    __shared__ __align__(16) unsigned short Al[128 * 32];
    __shared__ __align__(16) unsigned short Bh[128 * 32];
    __shared__ __align__(16) unsigned short Bl[128 * 32];

    int tid = threadIdx.x;
    int bm = blockIdx.y * 128;
    int bn = blockIdx.x * 128;
    int lane = tid & 63;
    int wv = tid >> 6;
    int wm = wv >> 1, wn = wv & 1;
    int ml = lane & 15, kq = lane >> 4;

    f4 acc[4][4];
    #pragma unroll
    for (int i = 0; i < 4; ++i)
        #pragma unroll
        for (int j = 0; j < 4; ++j)
            acc[i][j] = (f4){0.f, 0.f, 0.f, 0.f};

    for (int kt = 0; kt < Kdim; kt += 32) {
        __syncthreads();
        #pragma unroll
        for (int j = 0; j < 4; ++j) {
            int c = tid + 256 * j;
            int m = c >> 3, k4 = c & 7;
            int li = m * 32 + k4 * 4;
            unsigned h0, l0, h1, l1;
            const float4 a = *(const float4*)(A + (size_t)(bm + m) * Kdim + kt + k4 * 4);
            split2pack(a.x, a.y, &h0, &l0);
            split2pack(a.z, a.w, &h1, &l1);
            *(uint2*)&Ah[li] = make_uint2(h0, h1);
            *(uint2*)&Al[li] = make_uint2(l0, l1);
            const float4 b = *(const float4*)(Bw + (size_t)(bn + m) * Kdim + kt + k4 * 4);
            split2pack(b.x, b.y, &h0, &l0);
            split2pack(b.z, b.w, &h1, &l1);
            *(uint2*)&Bh[li] = make_uint2(h0, h1);
            *(uint2*)&Bl[li] = make_uint2(l0, l1);
        }
        __syncthreads();
        bfrag ah[4], al[4], bh[4], bl[4];
        #pragma unroll
        for (int i = 0; i < 4; ++i) {
            int arow = wm * 64 + i * 16 + ml;
            ah[i] = *(const bfrag*)&Ah[arow * 32 + kq * 8];
            al[i] = *(const bfrag*)&Al[arow * 32 + kq * 8];
            int brow = wn * 64 + i * 16 + ml;
            bh[i] = *(const bfrag*)&Bh[brow * 32 + kq * 8];
            bl[i] = *(const bfrag*)&Bl[brow * 32 + kq * 8];
        }
        #pragma unroll
        for (int mi = 0; mi < 4; ++mi)
            #pragma unroll
            for (int ni = 0; ni < 4; ++ni) {
                acc[mi][ni] = __builtin_amdgcn_mfma_f32_16x16x32_bf16(ah[mi], bh[ni], acc[mi][ni], 0, 0, 0);
                acc[mi][ni] = __builtin_amdgcn_mfma_f32_16x16x32_bf16(al[mi], bh[ni], acc[mi][ni], 0, 0, 0);
                acc[mi][ni] = __builtin_amdgcn_mfma_f32_16x16x32_bf16(ah[mi], bl[ni], acc[mi][ni], 0, 0, 0);
            }
    }
    #pragma unroll
    for (int ni = 0; ni < 4; ++ni) {
        int col = bn + wn * 64 + ni * 16 + ml;
        float bv = bias[col];
        #pragma unroll
        for (int mi = 0; mi < 4; ++mi) {
            int row0 = bm + wm * 64 + mi * 16 + kq * 4;
            #pragma unroll
            for (int r = 0; r < 4; ++r) {
                float o = acc[mi][ni][r] + bv;
                if (relu) o = fmaxf(o, 0.f);
                C[(size_t)(row0 + r) * Ncols + col] = o;
            }
        }
    }
}

// ---------------- MFMA key side ----------------
// grid (16, 64): x = n-split (256 rows), y = bh. 4 waves.
// phase1: td-tile [n16][m16] = mfma(Kfrag, Pfrag): lane: m = mt*16+ml fixed, n = w*16+quad*4+r
// phase2: Cu-tile [m16][dh16] = mfma(Ufrag, Vfrag): wave w owns m-tile w per chunk
__global__ __launch_bounds__(256) void kside(
    const float* __restrict__ Kin, const float* __restrict__ Vin,
    const float* __restrict__ proj,
    float* __restrict__ S_u, float* __restrict__ C_u,
    float* __restrict__ Vsum, unsigned int* __restrict__ mxp)
{
    __shared__ __align__(16) unsigned short Kh[64 * KP_], Kl[64 * KP_];   // [n][d]
    __shared__ __align__(16) unsigned short VT[64 * KP_];                 // [dh][n] bf16 RNE
    __shared__ __align__(16) unsigned short Ph[64 * KP_], Pl[64 * KP_];   // [m][d]
    __shared__ __align__(16) unsigned short Us[64 * KP_];                 // [m][n] bf16 RNE
    __shared__ __align__(16) float Ssum[MP_];
    __shared__ float diag[64];
    float* redf = (float*)Us;   // scratch reuse (lifetimes separated by barriers)

    int bh = blockIdx.y, b = bh >> 4, h = bh & 15;
    int n0 = blockIdx.x * 256;
    int tid = threadIdx.x, lane = tid & 63, w = tid >> 6;
    int ml = lane & 15, quad = lane >> 4;

    for (int i = tid; i < MP_; i += 256) Ssum[i] = 0.f;

    f4 acc[5][4];
    #pragma unroll
    for (int i = 0; i < 5; ++i)
        #pragma unroll
        for (int j = 0; j < 4; ++j) acc[i][j] = (f4){0.f, 0.f, 0.f, 0.f};
    float vs[4] = {0.f, 0.f, 0.f, 0.f};
    float lmax = -1e30f;

    for (int nc = 0; nc < 4; ++nc) {
        __syncthreads();
        #pragma unroll
        for (int l = 0; l < 4; ++l) {
            int idx = tid + 256 * l;
            int r = idx >> 4;
            int d4 = (idx & 15) * 4;
            size_t g = ((size_t)(b * N_ + n0 + nc * 64 + r)) * D_ + h * DH_ + d4;
            const float4 kv = *(const float4*)(Kin + g);
            redf[r * 17 + (tid & 15)] = kv.x * kv.x + kv.y * kv.y + kv.z * kv.z + kv.w * kv.w;
            unsigned h0, l0, h1, l1;
            split2pack(kv.x * DN_, kv.y * DN_, &h0, &l0);
            split2pack(kv.z * DN_, kv.w * DN_, &h1, &l1);
            *(uint2*)&Kh[r * KP_ + d4] = make_uint2(h0, h1);
            *(uint2*)&Kl[r * KP_ + d4] = make_uint2(l0, l1);
            const float4 vv = *(const float4*)(Vin + g);
            vs[0] += vv.x; vs[1] += vv.y; vs[2] += vv.z; vs[3] += vv.w;
            VT[(d4 + 0) * KP_ + r] = bf16rne(vv.x);
            VT[(d4 + 1) * KP_ + r] = bf16rne(vv.y);
            VT[(d4 + 2) * KP_ + r] = bf16rne(vv.z);
            VT[(d4 + 3) * KP_ + r] = bf16rne(vv.w);
        }
        __syncthreads();
        if (tid < 64) {
            float s = 0.f;
            #pragma unroll
            for (int p = 0; p < 16; ++p) s += redf[tid * 17 + p];
            diag[tid] = s * 0.0625f;
        }
        __syncthreads();

        bfrag kh0 = *(const bfrag*)&Kh[(w * 16 + ml) * KP_ + quad * 8];
        bfrag kl0 = *(const bfrag*)&Kl[(w * 16 + ml) * KP_ + quad * 8];
        bfrag kh1 = *(const bfrag*)&Kh[(w * 16 + ml) * KP_ + 32 + quad * 8];
        bfrag kl1 = *(const bfrag*)&Kl[(w * 16 + ml) * KP_ + 32 + quad * 8];
        float dgv[4];
        #pragma unroll
        for (int r = 0; r < 4; ++r) dgv[r] = diag[w * 16 + quad * 4 + r];

        for (int mc = 0; mc < 5; ++mc) {
            #pragma unroll
            for (int l = 0; l < 4; ++l) {
                int idx = tid + 256 * l;
                int m = idx >> 4, d4 = (idx & 15) * 4;
                int mg = mc * 64 + m;
                float4 p = make_float4(0.f, 0.f, 0.f, 0.f);
                if (mg < M_) p = *(const float4*)(proj + mg * 64 + d4);
                unsigned h0, l0, h1, l1;
                split2pack(p.x, p.y, &h0, &l0);
                split2pack(p.z, p.w, &h1, &l1);
                *(uint2*)&Ph[m * KP_ + d4] = make_uint2(h0, h1);
                *(uint2*)&Pl[m * KP_ + d4] = make_uint2(l0, l1);
            }
            __syncthreads();
            // phase 1
            #pragma unroll
            for (int mt = 0; mt < 4; ++mt) {
                int mrow = mt * 16 + ml;
                bfrag ph0 = *(const bfrag*)&Ph[mrow * KP_ + quad * 8];
                bfrag pl0 = *(const bfrag*)&Pl[mrow * KP_ + quad * 8];
                bfrag ph1 = *(const bfrag*)&Ph[mrow * KP_ + 32 + quad * 8];
                bfrag pl1 = *(const bfrag*)&Pl[mrow * KP_ + 32 + quad * 8];
                f4 t = (f4){0.f, 0.f, 0.f, 0.f};
                t = __builtin_amdgcn_mfma_f32_16x16x32_bf16(kh0, ph0, t, 0, 0, 0);
                t = __builtin_amdgcn_mfma_f32_16x16x32_bf16(kl0, ph0, t, 0, 0, 0);
                t = __builtin_amdgcn_mfma_f32_16x16x32_bf16(kh0, pl0, t, 0, 0, 0);
                t = __builtin_amdgcn_mfma_f32_16x16x32_bf16(kh1, ph1, t, 0, 0, 0);
                t = __builtin_amdgcn_mfma_f32_16x16x32_bf16(kl1, ph1, t, 0, 0, 0);
                t = __builtin_amdgcn_mfma_f32_16x16x32_bf16(kh1, pl1, t, 0, 0, 0);
                bool mv = (mc * 64 + mrow) < M_;
                float su = 0.f;
                unsigned short up[4];
                #pragma unroll
                for (int r = 0; r < 4; ++r) {
                    float u = 0.f;
                    if (mv) {
                        float tt = t[r];
                        lmax = fmaxf(lmax, tt);
                        u = __expf(tt - dgv[r]);
                    }
                    su += u;
                    up[r] = bf16rne(u);
                }
                if (mv) atomicAdd(&Ssum[mc * 64 + mrow], su);
                unsigned w0 = (unsigned)up[0] | ((unsigned)up[1] << 16);
                unsigned w1 = (unsigned)up[2] | ((unsigned)up[3] << 16);
                *(uint2*)&Us[mrow * KP_ + w * 16 + quad * 4] = make_uint2(w0, w1);
            }
            __syncthreads();
            // phase 2: wave w -> m-tile w
            bfrag ua0 = *(const bfrag*)&Us[(w * 16 + ml) * KP_ + quad * 8];
            bfrag ua1 = *(const bfrag*)&Us[(w * 16 + ml) * KP_ + 32 + quad * 8];
            #pragma unroll
            for (int dt = 0; dt < 4; ++dt) {
                bfrag vb0 = *(const bfrag*)&VT[(dt * 16 + ml) * KP_ + quad * 8];
                bfrag vb1 = *(const bfrag*)&VT[(dt * 16 + ml) * KP_ + 32 + quad * 8];
                acc[mc][dt] = __builtin_amdgcn_mfma_f32_16x16x32_bf16(ua0, vb0, acc[mc][dt], 0, 0, 0);
                acc[mc][dt] = __builtin_amdgcn_mfma_f32_16x16x32_bf16(ua1, vb1, acc[mc][dt], 0, 0, 0);
            }
            __syncthreads();
        }
    }
    // epilogue: C_u
    #pragma unroll
    for (int mc = 0; mc < 5; ++mc)
        #pragma unroll
        for (int dt = 0; dt < 4; ++dt)
            #pragma unroll
            for (int r = 0; r < 4; ++r) {
                int m = mc * 64 + w * 16 + quad * 4 + r;
                if (m < M_)
                    atomicAdd(C_u + ((size_t)bh * M_ + m) * 64 + dt * 16 + ml, acc[mc][dt][r]);
            }
    __syncthreads();
    for (int m = tid; m < M_; m += 256)
        atomicAdd(S_u + bh * M_ + m, Ssum[m]);
    // lmax
    #pragma unroll
    for (int off = 32; off; off >>= 1) lmax = fmaxf(lmax, __shfl_xor(lmax, off));
    __syncthreads();
    if (lane == 0) redf[w] = lmax;
    __syncthreads();
    if (tid == 0) {
        float mx = fmaxf(fmaxf(redf[0], redf[1]), fmaxf(redf[2], redf[3]));
        atomicMax(mxp + bh, f2ord(mx));
    }
    // Vsum: per-thread vs[] at dh = (tid&15)*4 + j
    for (int j = 0; j < 4; ++j) {
        __syncthreads();
        redf[tid] = vs[j];
        __syncthreads();
        if (tid < 16) {
            float s = 0.f;
            #pragma unroll
            for (int p = 0; p < 16; ++p) s += redf[tid + 16 * p];
            atomicAdd(Vsum + bh * 64 + tid * 4 + j, s);
        }
    }
}

// ---------------- finalize: ks (320 padded), ctxT split bf16 [bh][dh][320], Cs, kss ----------------
__global__ __launch_bounds__(256) void finalize_kernel(
    const float* __restrict__ S_u, const float* __restrict__ C_u,
    const float* __restrict__ Vsum, const unsigned* __restrict__ mxp,
    float* __restrict__ ksum_f, unsigned short* __restrict__ ctxTh,
    unsigned short* __restrict__ ctxTl, float* __restrict__ Cs, float* __restrict__ kss)
{
    __shared__ float red[256];
    int bh = blockIdx.x;
    int tid = threadIdx.x;
    float emx = __expf(-ord2f(mxp[bh]));
    for (int i = tid; i < 64 * MP_; i += 256) {
        int dh = i / MP_, m = i - dh * MP_;
        float v = 0.f;
        if (m < M_)
            v = RATIO_ * (emx * C_u[((size_t)bh * M_ + m) * 64 + dh] + EPS_ * Vsum[bh * 64 + dh]);
        unsigned u = __float_as_uint(v);
        float lo = v - __uint_as_float(u & 0xffff0000u);
        size_t dst = ((size_t)(bh * 64 + dh)) * MP_ + m;
        ctxTh[dst] = (unsigned short)(u >> 16);
        ctxTl[dst] = (unsigned short)(__float_as_uint(lo) >> 16);
    }
    for (int m = tid; m < MP_; m += 256)
        ksum_f[bh * MP_ + m] = (m < M_) ? RATIO_ * (emx * S_u[bh * M_ + m] + EPS_ * (float)N_) : 0.f;
    {
        int dh = tid & 63, part = tid >> 6;
        float s = 0.f;
        for (int m = part; m < M_; m += 4)
            s += RATIO_ * (emx * C_u[((size_t)bh * M_ + m) * 64 + dh] + EPS_ * Vsum[bh * 64 + dh]);
        red[tid] = s;
    }
    __syncthreads();
    if (tid < 64) Cs[bh * 64 + tid] = red[tid] + red[tid + 64] + red[tid + 128] + red[tid + 192];
    __syncthreads();
    {
        float s = 0.f;
        for (int m = tid; m < M_; m += 256)
            s += RATIO_ * (emx * S_u[bh * M_ + m] + EPS_ * (float)N_);
        red[tid] = s;
    }
    __syncthreads();
    for (int s = 128; s > 0; s >>= 1) {
        if (tid < s) red[tid] += red[tid + s];
        __syncthreads();
    }
    if (tid == 0) kss[bh] = red[0];
}

// ---------------- MFMA query side ----------------
// grid (64, 64): x = n-tile (64 rows), y = bh. 4 waves, wave w = n-stripe w.
// phase1 (transposed): td-tile [m16][n16] = mfma(Pfrag, Qfrag): lane: n = w*16+ml FIXED, m = mt*16+quad*4+r
// phase2: out-tile [n16][dh16] = mfma(Ufrag, Cfrag) split-3
__global__ __launch_bounds__(256) void qattn(
    const float* __restrict__ Q, const float* __restrict__ proj,
    const float* __restrict__ ksum_f, const unsigned short* __restrict__ ctxTh,
    const unsigned short* __restrict__ ctxTl,
    const float* __restrict__ Cs, const float* __restrict__ kss,
    float* __restrict__ attn)
{
    __shared__ __align__(16) unsigned short Qh[64 * KP_], Ql[64 * KP_];   // [n][d]
    __shared__ __align__(16) unsigned short Ph[64 * KP_], Pl[64 * KP_];   // proj [m][d], then ctxT [dh][m]
    __shared__ __align__(16) unsigned short Uh[64 * KP_], Ul[64 * KP_];   // [n][m]
    __shared__ __align__(16) float ks[MP_];
    __shared__ float diag[64];
    float* redf = (float*)Uh;

    int bh = blockIdx.y, b = bh >> 4, h = bh & 15;
    int n0 = blockIdx.x * 64;
    int tid = threadIdx.x, lane = tid & 63, w = tid >> 6;
    int ml = lane & 15, quad = lane >> 4;

    #pragma unroll
    for (int l = 0; l < 4; ++l) {
        int idx = tid + 256 * l;
        int r = idx >> 4, d4 = (idx & 15) * 4;
        size_t g = ((size_t)(b * N_ + n0 + r)) * D_ + h * DH_ + d4;
        const float4 qv = *(const float4*)(Q + g);
        redf[r * 17 + (tid & 15)] = qv.x * qv.x + qv.y * qv.y + qv.z * qv.z + qv.w * qv.w;
        unsigned h0, l0, h1, l1;
        split2pack(qv.x * DN_, qv.y * DN_, &h0, &l0);
        split2pack(qv.z * DN_, qv.w * DN_, &h1, &l1);
        *(uint2*)&Qh[r * KP_ + d4] = make_uint2(h0, h1);
        *(uint2*)&Ql[r * KP_ + d4] = make_uint2(l0, l1);
    }
    for (int m = tid; m < MP_; m += 256) ks[m] = ksum_f[bh * MP_ + m];
    __syncthreads();
    if (tid < 64) {
        float s = 0.f;
        #pragma unroll
        for (int p = 0; p < 16; ++p) s += redf[tid * 17 + p];
        diag[tid] = s * 0.0625f;
    }
    __syncthreads();

    bfrag qh0 = *(const bfrag*)&Qh[(w * 16 + ml) * KP_ + quad * 8];
    bfrag ql0 = *(const bfrag*)&Ql[(w * 16 + ml) * KP_ + quad * 8];
    bfrag qh1 = *(const bfrag*)&Qh[(w * 16 + ml) * KP_ + 32 + quad * 8];
    bfrag ql1 = *(const bfrag*)&Ql[(w * 16 + ml) * KP_ + 32 + quad * 8];
    float dg = diag[w * 16 + ml];
    float dacc = 0.f, tmax = -1e30f;
    f4 oacc[4];
    #pragma unroll
    for (int i = 0; i < 4; ++i) oacc[i] = (f4){0.f, 0.f, 0.f, 0.f};

    for (int mc = 0; mc < 5; ++mc) {
        #pragma unroll
        for (int l = 0; l < 4; ++l) {
            int idx = tid + 256 * l;
            int m = idx >> 4, d4 = (idx & 15) * 4;
            int mg = mc * 64 + m;
            float4 p = make_float4(0.f, 0.f, 0.f, 0.f);
            if (mg < M_) p = *(const float4*)(proj + mg * 64 + d4);
            unsigned h0, l0, h1, l1;
            split2pack(p.x, p.y, &h0, &l0);
            split2pack(p.z, p.w, &h1, &l1);
            *(uint2*)&Ph[m * KP_ + d4] = make_uint2(h0, h1);
            *(uint2*)&Pl[m * KP_ + d4] = make_uint2(l0, l1);
        }
        __syncthreads();
        // phase 1 (td^T)
        #pragma unroll
        for (int mt = 0; mt < 4; ++mt) {
            int mrow = mt * 16 + ml;
            bfrag ph0 = *(const bfrag*)&Ph[mrow * KP_ + quad * 8];
            bfrag pl0 = *(const bfrag*)&Pl[mrow * KP_ + quad * 8];
            bfrag ph1 = *(const bfrag*)&Ph[mrow * KP_ + 32 + quad * 8];
            bfrag pl1 = *(const bfrag*)&Pl[mrow * KP_ + 32 + quad * 8];
            f4 t = (f4){0.f, 0.f, 0.f, 0.f};
            t = __builtin_amdgcn_mfma_f32_16x16x32_bf16(ph0, qh0, t, 0, 0, 0);
            t = __builtin_amdgcn_mfma_f32_16x16x32_bf16(pl0, qh0, t, 0, 0, 0);
            t = __builtin_amdgcn_mfma_f32_16x16x32_bf16(ph0, ql0, t, 0, 0, 0);
            t = __builtin_amdgcn_mfma_f32_16x16x32_bf16(ph1, qh1, t, 0, 0, 0);
            t = __builtin_amdgcn_mfma_f32_16x16x32_bf16(pl1, qh1, t, 0, 0, 0);
            t = __builtin_amdgcn_mfma_f32_16x16x32_bf16(ph1, ql1, t, 0, 0, 0);
            const float4 ksv = *(const float4*)&ks[mc * 64 + mt * 16 + quad * 4];
            float ksa[4] = {ksv.x, ksv.y, ksv.z, ksv.w};
            unsigned short uh4[4], ul4[4];
            #pragma unroll
            for (int r = 0; r < 4; ++r) {
                int mg = mc * 64 + mt * 16 + quad * 4 + r;
                float tt = t[r];
                float u = __expf(tt - dg);
                if (mg < M_) tmax = fmaxf(tmax, tt);
                dacc = fmaf(u, ksa[r], dacc);          // ks=0 for pad m
                unsigned uu = __float_as_uint(u);
                float lo = u - __uint_as_float(uu & 0xffff0000u);
                uh4[r] = (unsigned short)(uu >> 16);
                ul4[r] = (unsigned short)(__float_as_uint(lo) >> 16);
            }
            unsigned a0 = (unsigned)uh4[0] | ((unsigned)uh4[1] << 16);
            unsigned a1 = (unsigned)uh4[2] | ((unsigned)uh4[3] << 16);
            unsigned b0 = (unsigned)ul4[0] | ((unsigned)ul4[1] << 16);
            unsigned b1 = (unsigned)ul4[2] | ((unsigned)ul4[3] << 16);
            *(uint2*)&Uh[(w * 16 + ml) * KP_ + mt * 16 + quad * 4] = make_uint2(a0, a1);
            *(uint2*)&Ul[(w * 16 + ml) * KP_ + mt * 16 + quad * 4] = make_uint2(b0, b1);
        }
        __syncthreads();
        // stage ctxT chunk into Ph/Pl (coalesced copy; pre-transposed/split by finalize)
        #pragma unroll
        for (int l = 0; l < 2; ++l) {
            int idx = tid + 256 * l;
            int dh = idx >> 3, m8 = (idx & 7) * 8;
            size_t src = ((size_t)(bh * 64 + dh)) * MP_ + mc * 64 + m8;
            *(uint4*)&Ph[dh * KP_ + m8] = *(const uint4*)(ctxTh + src);
            *(uint4*)&Pl[dh * KP_ + m8] = *(const uint4*)(ctxTl + src);
        }
        __syncthreads();
        // phase 2
        bfrag ua0h = *(const bfrag*)&Uh[(w * 16 + ml) * KP_ + quad * 8];
        bfrag ua0l = *(const bfrag*)&Ul[(w * 16 + ml) * KP_ + quad * 8];
        bfrag ua1h = *(const bfrag*)&Uh[(w * 16 + ml) * KP_ + 32 + quad * 8];
        bfrag ua1l = *(const bfrag*)&Ul[(w * 16 + ml) * KP_ + 32 + quad * 8];
        #pragma unroll
        for (int dt = 0; dt < 4; ++dt) {
            bfrag cb0h = *(const bfrag*)&Ph[(dt * 16 + ml) * KP_ + quad * 8];
            bfrag cb0l = *(const bfrag*)&Pl[(dt * 16 + ml) * KP_ + quad * 8];
            bfrag cb1h = *(const bfrag*)&Ph[(dt * 16 + ml) * KP_ + 32 + quad * 8];
            bfrag cb1l = *(const bfrag*)&Pl[(dt * 16 + ml) * KP_ + 32 + quad * 8];
            oacc[dt] = __builtin_amdgcn_mfma_f32_16x16x32_bf16(ua0h, cb0h, oacc[dt], 0, 0, 0);
            oacc[dt] = __builtin_amdgcn_mfma_f32_16x16x32_bf16(ua0l, cb0h, oacc[dt], 0, 0, 0);
            oacc[dt] = __builtin_amdgcn_mfma_f32_16x16x32_bf16(ua0h, cb0l, oacc[dt], 0, 0, 0);
            oacc[dt] = __builtin_amdgcn_mfma_f32_16x16x32_bf16(ua1h, cb1h, oacc[dt], 0, 0, 0);
            oacc[dt] = __builtin_amdgcn_mfma_f32_16x16x32_bf16(ua1l, cb1h, oacc[dt], 0, 0, 0);
            oacc[dt] = __builtin_amdgcn_mfma_f32_16x16x32_bf16(ua1h, cb1l, oacc[dt], 0, 0, 0);
        }
        __syncthreads();
    }
    // reduce per-row (n = w*16+ml) stats across quads
    dacc += __shfl_xor(dacc, 16); dacc += __shfl_xor(dacc, 32);
    tmax = fmaxf(tmax, __shfl_xor(tmax, 16));
    tmax = fmaxf(tmax, __shfl_xor(tmax, 32));
    float fac = EPS_ * __expf(tmax);
    float dinv = 1.f / (dacc + fac * kss[bh]);
    #pragma unroll
    for (int dt = 0; dt < 4; ++dt) {
        float csv = Cs[bh * 64 + dt * 16 + ml];
        #pragma unroll
        for (int r = 0; r < 4; ++r) {
            int srcl = quad * 4 + r;
            float dv = __shfl(dinv, srcl);
            float fv = __shfl(fac, srcl);
            float o = (oacc[dt][r] + fv * csv) * dv;
            int n = n0 + w * 16 + quad * 4 + r;
            attn[((size_t)(b * N_ + n)) * D_ + h * DH_ + dt * 16 + ml] = o;
        }
    }
}

// ---------------- launch ----------------
extern "C" void kernel_launch(void* const* d_in, const int* in_sizes, int n_in,
                              void* d_out, int out_size, void* d_ws, size_t ws_size,
                              hipStream_t stream)
{
    const float* x    = (const float*)d_in[0];
    const float* Wq   = (const float*)d_in[1];
    const float* bq   = (const float*)d_in[2];
    const float* Wk   = (const float*)d_in[3];
    const float* bk   = (const float*)d_in[4];
    const float* Wv   = (const float*)d_in[5];
    const float* bv   = (const float*)d_in[6];
    const float* Wo   = (const float*)d_in[7];
    const float* bo   = (const float*)d_in[8];
    const float* Wfc  = (const float*)d_in[9];
    const float* bfc  = (const float*)d_in[10];
    const float* proj = (const float*)d_in[11];
    float* out = (float*)d_out;

    float* ws = (float*)d_ws;
    const size_t nTok = (size_t)B_ * N_ * D_;
    const size_t nSu  = 64 * M_;
    const size_t nCu  = (size_t)64 * M_ * 64;
    const size_t nVs  = 64 * 64;
    const size_t nMx  = 64;
    const size_t nKsf = 64 * MP_;
    const size_t nCtx = (size_t)64 * MP_ * 64;   // floats; holds 2 ushort arrays of 64*64*MP_
    const size_t nCs  = 64 * 64;

    const size_t offQ   = 0;
    const size_t offK   = nTok;
    const size_t offV   = nTok * 2;
    const size_t offSu  = nTok * 3;
    const size_t offCu  = offSu + nSu;
    const size_t offVs  = offCu + nCu;
    const size_t offMx  = offVs + nVs;
    const size_t offKsf = offMx + nMx;
    const size_t offCtx = offKsf + nKsf;
    const size_t offCs  = offCtx + nCtx;
    const size_t offKss = offCs + nCs;

    float* Q    = ws + offQ;
    float* Kb   = ws + offK;
    float* Vb   = ws + offV;
    float* S_u  = ws + offSu;
    float* C_u  = ws + offCu;
    float* Vsum = ws + offVs;
    unsigned* mx = (unsigned*)(ws + offMx);
    float* ksf  = ws + offKsf;
    unsigned short* ctxTh = (unsigned short*)(ws + offCtx);
    unsigned short* ctxTl = ctxTh + (size_t)64 * 64 * MP_;
    float* Cs   = ws + offCs;
    float* kss  = ws + offKss;
    float* attn = Kb;   // K dead after kside
    float* hbuf = Vb;   // V dead after kside

    int nzero = (int)(nSu + nCu + nVs + nMx);
    zero_kernel<<<dim3((nzero + 255) / 256), dim3(256), 0, stream>>>(S_u, nzero);

    dim3 gg(D_ / 128, (B_ * N_) / 128);
    gemm3_nt<<<gg, dim3(256), 0, stream>>>(x, Wq, bq, Q, D_, D_, 0);
    gemm3_nt<<<gg, dim3(256), 0, stream>>>(x, Wk, bk, Kb, D_, D_, 0);
    gemm3_nt<<<gg, dim3(256), 0, stream>>>(x, Wv, bv, Vb, D_, D_, 0);

    kside<<<dim3(16, 64), dim3(256), 0, stream>>>(Kb, Vb, proj, S_u, C_u, Vsum, mx);
    finalize_kernel<<<dim3(64), dim3(256), 0, stream>>>(S_u, C_u, Vsum, mx, ksf, ctxTh, ctxTl, Cs, kss);
    qattn<<<dim3(64, 64), dim3(256), 0, stream>>>(Q, proj, ksf, ctxTh, ctxTl, Cs, kss, attn);

    gemm3_nt<<<gg, dim3(256), 0, stream>>>(attn, Wo, bo, hbuf, D_, D_, 0);
    gemm3_nt<<<gg, dim3(256), 0, stream>>>(hbuf, Wfc, bfc, out, D_, D_, 1);
}

// Round 6
// 1041.089 us; speedup vs baseline: 17.4621x; 1.2061x over previous
//
#include <hip/hip_runtime.h>
#include <math.h>

#define B_ 4
#define N_ 4096
#define D_ 1024
#define H_ 16
#define DH_ 64
#define M_ 266
#define MP_ 320   // M padded to 5 chunks of 64

#define DN_ 0.35355339059327373f      // 64^-0.25
#define RATIO_ 0.06131393394849658f   // 266^-0.5
#define EPS_ 1e-4f
#define KP_ 72    // ushort row stride
#define NSPLIT_ 16
#define PARTSZ_ ((size_t)64 * M_ * 64)   // one C_u partial (all bh)

typedef __attribute__((ext_vector_type(8))) short bfrag;
typedef __attribute__((ext_vector_type(4))) float f4;

__device__ __forceinline__ unsigned f2ord(float f) {
    unsigned u = __float_as_uint(f);
    return (u & 0x80000000u) ? ~u : (u | 0x80000000u);
}
__device__ __forceinline__ float ord2f(unsigned u) {
    unsigned b = (u & 0x80000000u) ? (u & 0x7fffffffu) : ~u;
    return __uint_as_float(b);
}

__global__ void zero_kernel(float* __restrict__ p, int n) {
    int i = blockIdx.x * 256 + threadIdx.x;
    if (i < n) p[i] = 0.f;
}

__device__ __forceinline__ void split2pack(float x, float y, unsigned* hp, unsigned* lp) {
    unsigned ux = __float_as_uint(x), uy = __float_as_uint(y);
    float hx = __uint_as_float(ux & 0xffff0000u);
    float hy = __uint_as_float(uy & 0xffff0000u);
    float lx = x - hx, ly = y - hy;
    *hp = (ux >> 16) | (uy & 0xffff0000u);
    *lp = (__float_as_uint(lx) >> 16) | (__float_as_uint(ly) & 0xffff0000u);
}
__device__ __forceinline__ unsigned short bf16rne(float x) {
    unsigned u = __float_as_uint(x);
    return (unsigned short)((u + 0x7fffu + ((u >> 16) & 1u)) >> 16);
}

// ---------------- split-bf16 3-product MFMA GEMM (Wo / Wfc) ----------------
__global__ __launch_bounds__(256) void gemm3_nt(const float* __restrict__ A,
        const float* __restrict__ Bw, const float* __restrict__ bias,
        float* __restrict__ C, int Kdim, int Ncols, int relu)
{
    __shared__ __align__(16) unsigned short Ah[128 * 32];
    __shared__ __align__(16) unsigned short Al[128 * 32];
    __shared__ __align__(16) unsigned short Bh[128 * 32];
    __shared__ __align__(16) unsigned short Bl[128 * 32];

    int tid = threadIdx.x;
    int bm = blockIdx.y * 128;
    int bn = blockIdx.x * 128;
    int lane = tid & 63;
    int wv = tid >> 6;
    int wm = wv >> 1, wn = wv & 1;
    int ml = lane & 15, kq = lane >> 4;

    f4 acc[4][4];
    #pragma unroll
    for (int i = 0; i < 4; ++i)
        #pragma unroll
        for (int j = 0; j < 4; ++j)
            acc[i][j] = (f4){0.f, 0.f, 0.f, 0.f};

    for (int kt = 0; kt < Kdim; kt += 32) {
        __syncthreads();
        #pragma unroll
        for (int j = 0; j < 4; ++j) {
            int c = tid + 256 * j;
            int m = c >> 3, k4 = c & 7;
            int li = m * 32 + k4 * 4;
            unsigned h0, l0, h1, l1;
            const float4 a = *(const float4*)(A + (size_t)(bm + m) * Kdim + kt + k4 * 4);
            split2pack(a.x, a.y, &h0, &l0);
            split2pack(a.z, a.w, &h1, &l1);
            *(uint2*)&Ah[li] = make_uint2(h0, h1);
            *(uint2*)&Al[li] = make_uint2(l0, l1);
            const float4 b = *(const float4*)(Bw + (size_t)(bn + m) * Kdim + kt + k4 * 4);
            split2pack(b.x, b.y, &h0, &l0);
            split2pack(b.z, b.w, &h1, &l1);
            *(uint2*)&Bh[li] = make_uint2(h0, h1);
            *(uint2*)&Bl[li] = make_uint2(l0, l1);
        }
        __syncthreads();
        bfrag ah[4], al[4], bh[4], bl[4];
        #pragma unroll
        for (int i = 0; i < 4; ++i) {
            int arow = wm * 64 + i * 16 + ml;
            ah[i] = *(const bfrag*)&Ah[arow * 32 + kq * 8];
            al[i] = *(const bfrag*)&Al[arow * 32 + kq * 8];
            int brow = wn * 64 + i * 16 + ml;
            bh[i] = *(const bfrag*)&Bh[brow * 32 + kq * 8];
            bl[i] = *(const bfrag*)&Bl[brow * 32 + kq * 8];
        }
        #pragma unroll
        for (int mi = 0; mi < 4; ++mi)
            #pragma unroll
            for (int ni = 0; ni < 4; ++ni) {
                acc[mi][ni] = __builtin_amdgcn_mfma_f32_16x16x32_bf16(ah[mi], bh[ni], acc[mi][ni], 0, 0, 0);
                acc[mi][ni] = __builtin_amdgcn_mfma_f32_16x16x32_bf16(al[mi], bh[ni], acc[mi][ni], 0, 0, 0);
                acc[mi][ni] = __builtin_amdgcn_mfma_f32_16x16x32_bf16(ah[mi], bl[ni], acc[mi][ni], 0, 0, 0);
            }
    }
    #pragma unroll
    for (int ni = 0; ni < 4; ++ni) {
        int col = bn + wn * 64 + ni * 16 + ml;
        float bv = bias[col];
        #pragma unroll
        for (int mi = 0; mi < 4; ++mi) {
            int row0 = bm + wm * 64 + mi * 16 + kq * 4;
            #pragma unroll
            for (int r = 0; r < 4; ++r) {
                float o = acc[mi][ni][r] + bv;
                if (relu) o = fmaxf(o, 0.f);
                C[(size_t)(row0 + r) * Ncols + col] = o;
            }
        }
    }
}

// ---------------- fused QKV GEMM: one dispatch, 3 weight sets ----------------
__global__ __launch_bounds__(256) void gemm3_qkv(const float* __restrict__ A,
        const float* __restrict__ W0, const float* __restrict__ W1, const float* __restrict__ W2,
        const float* __restrict__ b0, const float* __restrict__ b1, const float* __restrict__ b2,
        float* __restrict__ C0, float* __restrict__ C1, float* __restrict__ C2)
{
    __shared__ __align__(16) unsigned short Ah[128 * 32];
    __shared__ __align__(16) unsigned short Al[128 * 32];
    __shared__ __align__(16) unsigned short Bh[128 * 32];
    __shared__ __align__(16) unsigned short Bl[128 * 32];

    int tid = threadIdx.x;
    int sel = blockIdx.x >> 3;               // 0..2 -> q,k,v
    int bn = (blockIdx.x & 7) * 128;
    int bm = blockIdx.y * 128;
    const float* Bw = (sel == 0) ? W0 : (sel == 1) ? W1 : W2;
    const float* bias = (sel == 0) ? b0 : (sel == 1) ? b1 : b2;
    float* C = (sel == 0) ? C0 : (sel == 1) ? C1 : C2;

    int lane = tid & 63;
    int wv = tid >> 6;
    int wm = wv >> 1, wn = wv & 1;
    int ml = lane & 15, kq = lane >> 4;

    f4 acc[4][4];
    #pragma unroll
    for (int i = 0; i < 4; ++i)
        #pragma unroll
        for (int j = 0; j < 4; ++j)
            acc[i][j] = (f4){0.f, 0.f, 0.f, 0.f};

    for (int kt = 0; kt < D_; kt += 32) {
        __syncthreads();
        #pragma unroll
        for (int j = 0; j < 4; ++j) {
            int c = tid + 256 * j;
            int m = c >> 3, k4 = c & 7;
            int li = m * 32 + k4 * 4;
            unsigned h0, l0, h1, l1;
            const float4 a = *(const float4*)(A + (size_t)(bm + m) * D_ + kt + k4 * 4);
            split2pack(a.x, a.y, &h0, &l0);
            split2pack(a.z, a.w, &h1, &l1);
            *(uint2*)&Ah[li] = make_uint2(h0, h1);
            *(uint2*)&Al[li] = make_uint2(l0, l1);
            const float4 b = *(const float4*)(Bw + (size_t)(bn + m) * D_ + kt + k4 * 4);
            split2pack(b.x, b.y, &h0, &l0);
            split2pack(b.z, b.w, &h1, &l1);
            *(uint2*)&Bh[li] = make_uint2(h0, h1);
            *(uint2*)&Bl[li] = make_uint2(l0, l1);
        }
        __syncthreads();
        bfrag ah[4], al[4], bh[4], bl[4];
        #pragma unroll
        for (int i = 0; i < 4; ++i) {
            int arow = wm * 64 + i * 16 + ml;
            ah[i] = *(const bfrag*)&Ah[arow * 32 + kq * 8];
            al[i] = *(const bfrag*)&Al[arow * 32 + kq * 8];
            int brow = wn * 64 + i * 16 + ml;
            bh[i] = *(const bfrag*)&Bh[brow * 32 + kq * 8];
            bl[i] = *(const bfrag*)&Bl[brow * 32 + kq * 8];
        }
        #pragma unroll
        for (int mi = 0; mi < 4; ++mi)
            #pragma unroll
            for (int ni = 0; ni < 4; ++ni) {
                acc[mi][ni] = __builtin_amdgcn_mfma_f32_16x16x32_bf16(ah[mi], bh[ni], acc[mi][ni], 0, 0, 0);
                acc[mi][ni] = __builtin_amdgcn_mfma_f32_16x16x32_bf16(al[mi], bh[ni], acc[mi][ni], 0, 0, 0);
                acc[mi][ni] = __builtin_amdgcn_mfma_f32_16x16x32_bf16(ah[mi], bl[ni], acc[mi][ni], 0, 0, 0);
            }
    }
    #pragma unroll
    for (int ni = 0; ni < 4; ++ni) {
        int col = bn + wn * 64 + ni * 16 + ml;
        float bv = bias[col];
        #pragma unroll
        for (int mi = 0; mi < 4; ++mi) {
            int row0 = bm + wm * 64 + mi * 16 + kq * 4;
            #pragma unroll
            for (int r = 0; r < 4; ++r)
                C[(size_t)(row0 + r) * D_ + col] = acc[mi][ni][r] + bv;
        }
    }
}

// ---------------- MFMA key side, atomic-free C_u, single-bf16 phase1 ----------------
// grid (NSPLIT_=16, 64): x = n-split (256 rows), y = bh. 4 waves.
__global__ __launch_bounds__(256) void kside(
    const float* __restrict__ Kin, const float* __restrict__ Vin,
    const float* __restrict__ proj,
    float* __restrict__ S_u, float* __restrict__ Cpart, float* __restrict__ C_u,
    float* __restrict__ Vsum, unsigned int* __restrict__ mxp)
{
    __shared__ __align__(16) unsigned short Kh[64 * KP_];      // [n][d] bf16 RNE (pre-scaled by dn)
    __shared__ __align__(16) unsigned short VT[64 * KP_];      // [dh][n] bf16 RNE
    __shared__ __align__(16) unsigned short Ph[2][64 * KP_];   // proj [m][d] bf16 RNE, ping-pong
    __shared__ __align__(16) unsigned short Us[64 * KP_];      // [m][n] bf16 RNE
    __shared__ __align__(16) float Ssum[MP_];
    __shared__ float diag[64];
    float* redf = (float*)Us;   // overlay (lifetimes separated by barriers)

    int bh = blockIdx.y, b = bh >> 4, h = bh & 15;
    int s = blockIdx.x;
    int n0 = s * 256;
    int tid = threadIdx.x, lane = tid & 63, w = tid >> 6;
    int ml = lane & 15, quad = lane >> 4;

    float* dstC = (s < NSPLIT_ - 1) ? (Cpart + (size_t)s * PARTSZ_) : C_u;

    for (int i = tid; i < MP_; i += 256) Ssum[i] = 0.f;

    f4 acc[5][4];
    #pragma unroll
    for (int i = 0; i < 5; ++i)
        #pragma unroll
        for (int j = 0; j < 4; ++j) acc[i][j] = (f4){0.f, 0.f, 0.f, 0.f};
    float vs[4] = {0.f, 0.f, 0.f, 0.f};
    float lmax = -1e30f;

    for (int nc = 0; nc < 4; ++nc) {
        __syncthreads();
        // stage K (RNE, *dn), V^T (RNE), diag partials, and proj chunk 0
        #pragma unroll
        for (int l = 0; l < 4; ++l) {
            int idx = tid + 256 * l;
            int r = idx >> 4;
            int d4 = (idx & 15) * 4;
            size_t g = ((size_t)(b * N_ + n0 + nc * 64 + r)) * D_ + h * DH_ + d4;
            const float4 kv = *(const float4*)(Kin + g);
            redf[r * 17 + (tid & 15)] = kv.x * kv.x + kv.y * kv.y + kv.z * kv.z + kv.w * kv.w;
            unsigned w0 = (unsigned)bf16rne(kv.x * DN_) | ((unsigned)bf16rne(kv.y * DN_) << 16);
            unsigned w1 = (unsigned)bf16rne(kv.z * DN_) | ((unsigned)bf16rne(kv.w * DN_) << 16);
            *(uint2*)&Kh[r * KP_ + d4] = make_uint2(w0, w1);
            const float4 vv = *(const float4*)(Vin + g);
            vs[0] += vv.x; vs[1] += vv.y; vs[2] += vv.z; vs[3] += vv.w;
            VT[(d4 + 0) * KP_ + r] = bf16rne(vv.x);
            VT[(d4 + 1) * KP_ + r] = bf16rne(vv.y);
            VT[(d4 + 2) * KP_ + r] = bf16rne(vv.z);
            VT[(d4 + 3) * KP_ + r] = bf16rne(vv.w);
        }
        {   // proj chunk 0 -> Ph[0]
            #pragma unroll
            for (int l = 0; l < 2; ++l) {
                int idx = tid + 256 * l;
                int m = idx >> 3, d8 = (idx & 7) * 8;
                const float4 p0 = *(const float4*)(proj + m * 64 + d8);
                const float4 p1 = *(const float4*)(proj + m * 64 + d8 + 4);
                unsigned a0 = (unsigned)bf16rne(p0.x) | ((unsigned)bf16rne(p0.y) << 16);
                unsigned a1 = (unsigned)bf16rne(p0.z) | ((unsigned)bf16rne(p0.w) << 16);
                unsigned a2 = (unsigned)bf16rne(p1.x) | ((unsigned)bf16rne(p1.y) << 16);
                unsigned a3 = (unsigned)bf16rne(p1.z) | ((unsigned)bf16rne(p1.w) << 16);
                *(uint4*)&Ph[0][m * KP_ + d8] = make_uint4(a0, a1, a2, a3);
            }
        }
        __syncthreads();
        if (tid < 64) {
            float ss = 0.f;
            #pragma unroll
            for (int p = 0; p < 16; ++p) ss += redf[tid * 17 + p];
            diag[tid] = ss * 0.0625f;
        }
        __syncthreads();

        bfrag kh0 = *(const bfrag*)&Kh[(w * 16 + ml) * KP_ + quad * 8];
        bfrag kh1 = *(const bfrag*)&Kh[(w * 16 + ml) * KP_ + 32 + quad * 8];
        float dgv[4];
        #pragma unroll
        for (int r = 0; r < 4; ++r) dgv[r] = diag[w * 16 + quad * 4 + r];

        for (int mc = 0; mc < 5; ++mc) {
            int pb = mc & 1;
            // prefetch next proj chunk (loads overlap phase-1 MFMA)
            float4 pf[4];
            if (mc < 4) {
                #pragma unroll
                for (int l = 0; l < 2; ++l) {
                    int idx = tid + 256 * l;
                    int m = idx >> 3, d8 = (idx & 7) * 8;
                    int mg = (mc + 1) * 64 + m;
                    if (mg < M_) {
                        pf[l * 2 + 0] = *(const float4*)(proj + mg * 64 + d8);
                        pf[l * 2 + 1] = *(const float4*)(proj + mg * 64 + d8 + 4);
                    } else {
                        pf[l * 2 + 0] = make_float4(0.f, 0.f, 0.f, 0.f);
                        pf[l * 2 + 1] = make_float4(0.f, 0.f, 0.f, 0.f);
                    }
                }
            }
            // phase 1: td[n][m] tiles, single-bf16
            #pragma unroll
            for (int mt = 0; mt < 4; ++mt) {
                int mrow = mt * 16 + ml;
                bfrag ph0 = *(const bfrag*)&Ph[pb][mrow * KP_ + quad * 8];
                bfrag ph1 = *(const bfrag*)&Ph[pb][mrow * KP_ + 32 + quad * 8];
                f4 t = (f4){0.f, 0.f, 0.f, 0.f};
                t = __builtin_amdgcn_mfma_f32_16x16x32_bf16(kh0, ph0, t, 0, 0, 0);
                t = __builtin_amdgcn_mfma_f32_16x16x32_bf16(kh1, ph1, t, 0, 0, 0);
                bool mv = (mc * 64 + mrow) < M_;
                float su = 0.f;
                unsigned short up[4];
                #pragma unroll
                for (int r = 0; r < 4; ++r) {
                    float u = 0.f;
                    if (mv) {
                        float tt = t[r];
                        lmax = fmaxf(lmax, tt);
                        u = __expf(tt - dgv[r]);
                    }
                    su += u;
                    up[r] = bf16rne(u);
                }
                su += __shfl_xor(su, 16);
                su += __shfl_xor(su, 32);
                if (mv && quad == 0) atomicAdd(&Ssum[mc * 64 + mrow], su);
                unsigned w0 = (unsigned)up[0] | ((unsigned)up[1] << 16);
                unsigned w1 = (unsigned)up[2] | ((unsigned)up[3] << 16);
                *(uint2*)&Us[mrow * KP_ + w * 16 + quad * 4] = make_uint2(w0, w1);
            }
            // store prefetched proj
            if (mc < 4) {
                #pragma unroll
                for (int l = 0; l < 2; ++l) {
                    int idx = tid + 256 * l;
                    int m = idx >> 3, d8 = (idx & 7) * 8;
                    const float4 p0 = pf[l * 2 + 0], p1 = pf[l * 2 + 1];
                    unsigned a0 = (unsigned)bf16rne(p0.x) | ((unsigned)bf16rne(p0.y) << 16);
                    unsigned a1 = (unsigned)bf16rne(p0.z) | ((unsigned)bf16rne(p0.w) << 16);
                    unsigned a2 = (unsigned)bf16rne(p1.x) | ((unsigned)bf16rne(p1.y) << 16);
                    unsigned a3 = (unsigned)bf16rne(p1.z) | ((unsigned)bf16rne(p1.w) << 16);
                    *(uint4*)&Ph[1 - pb][m * KP_ + d8] = make_uint4(a0, a1, a2, a3);
                }
            }
            __syncthreads();
            // phase 2: acc[mc] += Us^T-tile @ V
            bfrag ua0 = *(const bfrag*)&Us[(w * 16 + ml) * KP_ + quad * 8];
            bfrag ua1 = *(const bfrag*)&Us[(w * 16 + ml) * KP_ + 32 + quad * 8];
            #pragma unroll
            for (int dt = 0; dt < 4; ++dt) {
                bfrag vb0 = *(const bfrag*)&VT[(dt * 16 + ml) * KP_ + quad * 8];
                bfrag vb1 = *(const bfrag*)&VT[(dt * 16 + ml) * KP_ + 32 + quad * 8];
                acc[mc][dt] = __builtin_amdgcn_mfma_f32_16x16x32_bf16(ua0, vb0, acc[mc][dt], 0, 0, 0);
                acc[mc][dt] = __builtin_amdgcn_mfma_f32_16x16x32_bf16(ua1, vb1, acc[mc][dt], 0, 0, 0);
            }
            __syncthreads();
        }
    }
    // epilogue: C_u partial, PLAIN stores (no atomics)
    #pragma unroll
    for (int mc = 0; mc < 5; ++mc)
        #pragma unroll
        for (int dt = 0; dt < 4; ++dt)
            #pragma unroll
            for (int r = 0; r < 4; ++r) {
                int m = mc * 64 + w * 16 + quad * 4 + r;
                if (m < M_)
                    dstC[((size_t)bh * M_ + m) * 64 + dt * 16 + ml] = acc[mc][dt][r];
            }
    __syncthreads();
    for (int m = tid; m < M_; m += 256)
        atomicAdd(S_u + bh * M_ + m, Ssum[m]);
    #pragma unroll
    for (int off = 32; off; off >>= 1) lmax = fmaxf(lmax, __shfl_xor(lmax, off));
    __syncthreads();
    if (lane == 0) redf[w] = lmax;
    __syncthreads();
    if (tid == 0) {
        float mxv = fmaxf(fmaxf(redf[0], redf[1]), fmaxf(redf[2], redf[3]));
        atomicMax(mxp + bh, f2ord(mxv));
    }
    for (int j = 0; j < 4; ++j) {
        __syncthreads();
        redf[tid] = vs[j];
        __syncthreads();
        if (tid < 16) {
            float ss = 0.f;
            #pragma unroll
            for (int p = 0; p < 16; ++p) ss += redf[tid + 16 * p];
            atomicAdd(Vsum + bh * 64 + tid * 4 + j, ss);
        }
    }
}

// ---------------- finalize: sum 16 partials, build ks + ctxT(split) + Cs + kss ----------------
// grid (5, 64): x = m-chunk, y = bh
__global__ __launch_bounds__(256) void finalize_kernel(
    const float* __restrict__ S_u, const float* __restrict__ Cpart, const float* __restrict__ C_u,
    const float* __restrict__ Vsum, const unsigned* __restrict__ mxp,
    float* __restrict__ ksum_f, unsigned short* __restrict__ ctxTh,
    unsigned short* __restrict__ ctxTl, float* __restrict__ Cs, float* __restrict__ kss)
{
    __shared__ float T[64 * 65];
    __shared__ float red[256];
    int mc = blockIdx.x, bh = blockIdx.y;
    int tid = threadIdx.x;
    float emx = __expf(-ord2f(mxp[bh]));

    float csacc = 0.f;   // dh = tid&63 fixed across iterations
    #pragma unroll
    for (int i = 0; i < 16; ++i) {
        int idx = i * 256 + tid;
        int dh = idx & 63, mloc = idx >> 6;
        int m = mc * 64 + mloc;
        float v = 0.f;
        if (m < M_) {
            size_t off = ((size_t)bh * M_ + m) * 64 + dh;
            float sacc = C_u[off];
            for (int sp = 0; sp < NSPLIT_ - 1; ++sp)
                sacc += Cpart[(size_t)sp * PARTSZ_ + off];
            v = RATIO_ * (emx * sacc + EPS_ * Vsum[bh * 64 + dh]);
        }
        T[mloc * 65 + dh] = v;
        csacc += v;
    }
    red[tid] = csacc;
    __syncthreads();
    if (tid < 64) atomicAdd(&Cs[bh * 64 + tid], red[tid] + red[tid + 64] + red[tid + 128] + red[tid + 192]);
    // ks + kss
    float ksl = 0.f;
    if (tid < 64) {
        int m = mc * 64 + tid;
        float kv = (m < M_) ? RATIO_ * (emx * S_u[bh * M_ + m] + EPS_ * (float)N_) : 0.f;
        ksum_f[bh * MP_ + m] = kv;
        ksl = kv;
    }
    __syncthreads();
    red[tid] = ksl;
    __syncthreads();
    if (tid == 0) {
        float ss = 0.f;
        for (int p = 0; p < 64; ++p) ss += red[p];
        atomicAdd(kss + bh, ss);
    }
    __syncthreads();
    // transposed split writes: ctxT[dh][m]
    #pragma unroll
    for (int i = 0; i < 8; ++i) {
        int idx = i * 256 + tid;
        int dh = idx >> 5, m2 = (idx & 31) * 2;
        float v0 = T[m2 * 65 + dh], v1 = T[(m2 + 1) * 65 + dh];
        unsigned u0 = __float_as_uint(v0), u1 = __float_as_uint(v1);
        float lo0 = v0 - __uint_as_float(u0 & 0xffff0000u);
        float lo1 = v1 - __uint_as_float(u1 & 0xffff0000u);
        size_t dst = ((size_t)(bh * 64 + dh)) * MP_ + mc * 64 + m2;
        *(unsigned*)&ctxTh[dst] = (u0 >> 16) | (u1 & 0xffff0000u);
        *(unsigned*)&ctxTl[dst] = (__float_as_uint(lo0) >> 16) | (__float_as_uint(lo1) & 0xffff0000u);
    }
}

// ---------------- MFMA query side (unchanged from round 5) ----------------
__global__ __launch_bounds__(256) void qattn(
    const float* __restrict__ Q, const float* __restrict__ proj,
    const float* __restrict__ ksum_f, const unsigned short* __restrict__ ctxTh,
    const unsigned short* __restrict__ ctxTl,
    const float* __restrict__ Cs, const float* __restrict__ kss,
    float* __restrict__ attn)
{
    __shared__ __align__(16) unsigned short Qh[64 * KP_], Ql[64 * KP_];
    __shared__ __align__(16) unsigned short Ph[64 * KP_], Pl[64 * KP_];
    __shared__ __align__(16) unsigned short Uh[64 * KP_], Ul[64 * KP_];
    __shared__ __align__(16) float ks[MP_];
    __shared__ float diag[64];
    float* redf = (float*)Uh;

    int bh = blockIdx.y, b = bh >> 4, h = bh & 15;
    int n0 = blockIdx.x * 64;
    int tid = threadIdx.x, lane = tid & 63, w = tid >> 6;
    int ml = lane & 15, quad = lane >> 4;

    #pragma unroll
    for (int l = 0; l < 4; ++l) {
        int idx = tid + 256 * l;
        int r = idx >> 4, d4 = (idx & 15) * 4;
        size_t g = ((size_t)(b * N_ + n0 + r)) * D_ + h * DH_ + d4;
        const float4 qv = *(const float4*)(Q + g);
        redf[r * 17 + (tid & 15)] = qv.x * qv.x + qv.y * qv.y + qv.z * qv.z + qv.w * qv.w;
        unsigned h0, l0, h1, l1;
        split2pack(qv.x * DN_, qv.y * DN_, &h0, &l0);
        split2pack(qv.z * DN_, qv.w * DN_, &h1, &l1);
        *(uint2*)&Qh[r * KP_ + d4] = make_uint2(h0, h1);
        *(uint2*)&Ql[r * KP_ + d4] = make_uint2(l0, l1);
    }
    for (int m = tid; m < MP_; m += 256) ks[m] = ksum_f[bh * MP_ + m];
    __syncthreads();
    if (tid < 64) {
        float s = 0.f;
        #pragma unroll
        for (int p = 0; p < 16; ++p) s += redf[tid * 17 + p];
        diag[tid] = s * 0.0625f;
    }
    __syncthreads();

    bfrag qh0 = *(const bfrag*)&Qh[(w * 16 + ml) * KP_ + quad * 8];
    bfrag ql0 = *(const bfrag*)&Ql[(w * 16 + ml) * KP_ + quad * 8];
    bfrag qh1 = *(const bfrag*)&Qh[(w * 16 + ml) * KP_ + 32 + quad * 8];
    bfrag ql1 = *(const bfrag*)&Ql[(w * 16 + ml) * KP_ + 32 + quad * 8];
    float dg = diag[w * 16 + ml];
    float dacc = 0.f, tmax = -1e30f;
    f4 oacc[4];
    #pragma unroll
    for (int i = 0; i < 4; ++i) oacc[i] = (f4){0.f, 0.f, 0.f, 0.f};

    for (int mc = 0; mc < 5; ++mc) {
        #pragma unroll
        for (int l = 0; l < 4; ++l) {
            int idx = tid + 256 * l;
            int m = idx >> 4, d4 = (idx & 15) * 4;
            int mg = mc * 64 + m;
            float4 p = make_float4(0.f, 0.f, 0.f, 0.f);
            if (mg < M_) p = *(const float4*)(proj + mg * 64 + d4);
            unsigned h0, l0, h1, l1;
            split2pack(p.x, p.y, &h0, &l0);
            split2pack(p.z, p.w, &h1, &l1);
            *(uint2*)&Ph[m * KP_ + d4] = make_uint2(h0, h1);
            *(uint2*)&Pl[m * KP_ + d4] = make_uint2(l0, l1);
        }
        __syncthreads();
        #pragma unroll
        for (int mt = 0; mt < 4; ++mt) {
            int mrow = mt * 16 + ml;
            bfrag ph0 = *(const bfrag*)&Ph[mrow * KP_ + quad * 8];
            bfrag pl0 = *(const bfrag*)&Pl[mrow * KP_ + quad * 8];
            bfrag ph1 = *(const bfrag*)&Ph[mrow * KP_ + 32 + quad * 8];
            bfrag pl1 = *(const bfrag*)&Pl[mrow * KP_ + 32 + quad * 8];
            f4 t = (f4){0.f, 0.f, 0.f, 0.f};
            t = __builtin_amdgcn_mfma_f32_16x16x32_bf16(ph0, qh0, t, 0, 0, 0);
            t = __builtin_amdgcn_mfma_f32_16x16x32_bf16(pl0, qh0, t, 0, 0, 0);
            t = __builtin_amdgcn_mfma_f32_16x16x32_bf16(ph0, ql0, t, 0, 0, 0);
            t = __builtin_amdgcn_mfma_f32_16x16x32_bf16(ph1, qh1, t, 0, 0, 0);
            t = __builtin_amdgcn_mfma_f32_16x16x32_bf16(pl1, qh1, t, 0, 0, 0);
            t = __builtin_amdgcn_mfma_f32_16x16x32_bf16(ph1, ql1, t, 0, 0, 0);
            const float4 ksv = *(const float4*)&ks[mc * 64 + mt * 16 + quad * 4];
            float ksa[4] = {ksv.x, ksv.y, ksv.z, ksv.w};
            unsigned short uh4[4], ul4[4];
            #pragma unroll
            for (int r = 0; r < 4; ++r) {
                int mg = mc * 64 + mt * 16 + quad * 4 + r;
                float tt = t[r];
                float u = __expf(tt - dg);
                if (mg < M_) tmax = fmaxf(tmax, tt);
                dacc = fmaf(u, ksa[r], dacc);
                unsigned uu = __float_as_uint(u);
                float lo = u - __uint_as_float(uu & 0xffff0000u);
                uh4[r] = (unsigned short)(uu >> 16);
                ul4[r] = (unsigned short)(__float_as_uint(lo) >> 16);
            }
            unsigned a0 = (unsigned)uh4[0] | ((unsigned)uh4[1] << 16);
            unsigned a1 = (unsigned)uh4[2] | ((unsigned)uh4[3] << 16);
            unsigned b0 = (unsigned)ul4[0] | ((unsigned)ul4[1] << 16);
            unsigned b1 = (unsigned)ul4[2] | ((unsigned)ul4[3] << 16);
            *(uint2*)&Uh[(w * 16 + ml) * KP_ + mt * 16 + quad * 4] = make_uint2(a0, a1);
            *(uint2*)&Ul[(w * 16 + ml) * KP_ + mt * 16 + quad * 4] = make_uint2(b0, b1);
        }
        __syncthreads();
        #pragma unroll
        for (int l = 0; l < 2; ++l) {
            int idx = tid + 256 * l;
            int dh = idx >> 3, m8 = (idx & 7) * 8;
            size_t src = ((size_t)(bh * 64 + dh)) * MP_ + mc * 64 + m8;
            *(uint4*)&Ph[dh * KP_ + m8] = *(const uint4*)(ctxTh + src);
            *(uint4*)&Pl[dh * KP_ + m8] = *(const uint4*)(ctxTl + src);
        }
        __syncthreads();
        bfrag ua0h = *(const bfrag*)&Uh[(w * 16 + ml) * KP_ + quad * 8];
        bfrag ua0l = *(const bfrag*)&Ul[(w * 16 + ml) * KP_ + quad * 8];
        bfrag ua1h = *(const bfrag*)&Uh[(w * 16 + ml) * KP_ + 32 + quad * 8];
        bfrag ua1l = *(const bfrag*)&Ul[(w * 16 + ml) * KP_ + 32 + quad * 8];
        #pragma unroll
        for (int dt = 0; dt < 4; ++dt) {
            bfrag cb0h = *(const bfrag*)&Ph[(dt * 16 + ml) * KP_ + quad * 8];
            bfrag cb0l = *(const bfrag*)&Pl[(dt * 16 + ml) * KP_ + quad * 8];
            bfrag cb1h = *(const bfrag*)&Ph[(dt * 16 + ml) * KP_ + 32 + quad * 8];
            bfrag cb1l = *(const bfrag*)&Pl[(dt * 16 + ml) * KP_ + 32 + quad * 8];
            oacc[dt] = __builtin_amdgcn_mfma_f32_16x16x32_bf16(ua0h, cb0h, oacc[dt], 0, 0, 0);
            oacc[dt] = __builtin_amdgcn_mfma_f32_16x16x32_bf16(ua0l, cb0h, oacc[dt], 0, 0, 0);
            oacc[dt] = __builtin_amdgcn_mfma_f32_16x16x32_bf16(ua0h, cb0l, oacc[dt], 0, 0, 0);
            oacc[dt] = __builtin_amdgcn_mfma_f32_16x16x32_bf16(ua1h, cb1h, oacc[dt], 0, 0, 0);
            oacc[dt] = __builtin_amdgcn_mfma_f32_16x16x32_bf16(ua1l, cb1h, oacc[dt], 0, 0, 0);
            oacc[dt] = __builtin_amdgcn_mfma_f32_16x16x32_bf16(ua1h, cb1l, oacc[dt], 0, 0, 0);
        }
        __syncthreads();
    }
    dacc += __shfl_xor(dacc, 16); dacc += __shfl_xor(dacc, 32);
    tmax = fmaxf(tmax, __shfl_xor(tmax, 16));
    tmax = fmaxf(tmax, __shfl_xor(tmax, 32));
    float fac = EPS_ * __expf(tmax);
    float dinv = 1.f / (dacc + fac * kss[bh]);
    #pragma unroll
    for (int dt = 0; dt < 4; ++dt) {
        float csv = Cs[bh * 64 + dt * 16 + ml];
        #pragma unroll
        for (int r = 0; r < 4; ++r) {
            int srcl = quad * 4 + r;
            float dv = __shfl(dinv, srcl);
            float fv = __shfl(fac, srcl);
            float o = (oacc[dt][r] + fv * csv) * dv;
            int n = n0 + w * 16 + quad * 4 + r;
            attn[((size_t)(b * N_ + n)) * D_ + h * DH_ + dt * 16 + ml] = o;
        }
    }
}

// ---------------- launch ----------------
extern "C" void kernel_launch(void* const* d_in, const int* in_sizes, int n_in,
                              void* d_out, int out_size, void* d_ws, size_t ws_size,
                              hipStream_t stream)
{
    const float* x    = (const float*)d_in[0];
    const float* Wq   = (const float*)d_in[1];
    const float* bq   = (const float*)d_in[2];
    const float* Wk   = (const float*)d_in[3];
    const float* bk   = (const float*)d_in[4];
    const float* Wv   = (const float*)d_in[5];
    const float* bv   = (const float*)d_in[6];
    const float* Wo   = (const float*)d_in[7];
    const float* bo   = (const float*)d_in[8];
    const float* Wfc  = (const float*)d_in[9];
    const float* bfc  = (const float*)d_in[10];
    const float* proj = (const float*)d_in[11];
    float* out = (float*)d_out;

    float* ws = (float*)d_ws;
    const size_t nTok = (size_t)B_ * N_ * D_;
    const size_t nSu  = 64 * M_;
    const size_t nCu  = (size_t)64 * M_ * 64;
    const size_t nVs  = 64 * 64;
    const size_t nMx  = 64;
    const size_t nKsf = 64 * MP_;
    const size_t nCtx = (size_t)64 * MP_ * 64;
    const size_t nCs  = 64 * 64;

    const size_t offQ   = 0;
    const size_t offK   = nTok;
    const size_t offV   = nTok * 2;
    const size_t offSu  = nTok * 3;
    const size_t offCu  = offSu + nSu;
    const size_t offVs  = offCu + nCu;
    const size_t offMx  = offVs + nVs;
    const size_t offKsf = offMx + nMx;
    const size_t offCtx = offKsf + nKsf;
    const size_t offCs  = offCtx + nCtx;
    const size_t offKss = offCs + nCs;

    float* Q    = ws + offQ;
    float* Kb   = ws + offK;
    float* Vb   = ws + offV;
    float* S_u  = ws + offSu;
    float* C_u  = ws + offCu;
    float* Vsum = ws + offVs;
    unsigned* mx = (unsigned*)(ws + offMx);
    float* ksf  = ws + offKsf;
    unsigned short* ctxTh = (unsigned short*)(ws + offCtx);
    unsigned short* ctxTl = ctxTh + (size_t)64 * 64 * MP_;
    float* Cs   = ws + offCs;
    float* kss  = ws + offKss;
    float* attn = Kb;   // K dead after kside
    float* hbuf = Vb;   // V dead after kside
    float* Cpart = out; // d_out as scratch for 15 C_u partials (rewritten by final GEMM)

    // zero S_u..kss (covers S_u, C_u, Vsum, mx, ksf, ctxT, Cs, kss)
    int nzero = (int)(nSu + nCu + nVs + nMx + nKsf + nCtx + nCs + 64);
    zero_kernel<<<dim3((nzero + 255) / 256), dim3(256), 0, stream>>>(S_u, nzero);

    gemm3_qkv<<<dim3(24, (B_ * N_) / 128), dim3(256), 0, stream>>>(
        x, Wq, Wk, Wv, bq, bk, bv, Q, Kb, Vb);

    kside<<<dim3(NSPLIT_, 64), dim3(256), 0, stream>>>(Kb, Vb, proj, S_u, Cpart, C_u, Vsum, mx);
    finalize_kernel<<<dim3(5, 64), dim3(256), 0, stream>>>(S_u, Cpart, C_u, Vsum, mx, ksf, ctxTh, ctxTl, Cs, kss);
    qattn<<<dim3(64, 64), dim3(256), 0, stream>>>(Q, proj, ksf, ctxTh, ctxTl, Cs, kss, attn);

    dim3 gg(D_ / 128, (B_ * N_) / 128);
    gemm3_nt<<<gg, dim3(256), 0, stream>>>(attn, Wo, bo, hbuf, D_, D_, 0);
    gemm3_nt<<<gg, dim3(256), 0, stream>>>(hbuf, Wfc, bfc, out, D_, D_, 1);
}